// Round 19
// baseline (1195.496 us; speedup 1.0000x reference)
//
#include <hip/hip_runtime.h>
#include <hip/hip_bf16.h>

#define Bb 4
#define Nn 384
#define Ee 768
#define Hh 32
#define Ff 3072
#define Ll 12
#define Ss 512
#define Mm (Nn*Bb)   // 1536 tokens

typedef __attribute__((ext_vector_type(8))) short bf16x8;
typedef __attribute__((ext_vector_type(4))) float f32x4;
typedef unsigned short u16;

__device__ __forceinline__ u16 f2b(float f) {
  union { float f; unsigned int i; } c; c.f = f;
  unsigned int x = c.i;
  return (u16)((x + 0x7fffu + ((x >> 16) & 1u)) >> 16); // RNE
}
__device__ __forceinline__ float b2f(u16 u) {
  union { unsigned int i; float f; } c; c.i = ((unsigned int)u) << 16; return c.f;
}
__device__ __forceinline__ unsigned pkcvt(float lo, float hi) {
  unsigned r;
  asm("v_cvt_pk_bf16_f32 %0, %1, %2" : "=v"(r) : "v"(lo), "v"(hi));
  return r;
}
__device__ __forceinline__ void gload_lds16(const void* g, void* l) {
  __builtin_amdgcn_global_load_lds((__attribute__((address_space(1))) void*)(g),
                                   (__attribute__((address_space(3))) void*)(l), 16, 0, 0);
}

// ---------------- embed body
__device__ __forceinline__ void embed_body(
    int r, const int* __restrict__ node_type, const float* __restrict__ nif,
    const int* __restrict__ in_deg, const int* __restrict__ out_deg,
    const float* __restrict__ node_emb, const float* __restrict__ ind_emb,
    const float* __restrict__ outd_emb,
    float* __restrict__ x, u16* __restrict__ xb)
{
  const int n = r / Bb, b = r % Bb;
  const int nt  = node_type[b*Nn + n];
  const int idg = in_deg[b*Nn + n];
  const int odg = out_deg[b*Nn + n];
  for (int c = threadIdx.x; c < Ee; c += 256) {
    float val = node_emb[(size_t)nt*Ee + c] + ind_emb[(size_t)idg*Ee + c]
              + outd_emb[(size_t)odg*Ee + c] + nif[((size_t)b*Nn + n)*Ee + c];
    x[(size_t)r*Ee + c] = val;
    xb[(size_t)r*Ee + c] = f2b(val);
  }
}

__global__ __launch_bounds__(256) void embed_kernel(
    const int* __restrict__ node_type, const float* __restrict__ nif,
    const int* __restrict__ in_deg, const int* __restrict__ out_deg,
    const float* __restrict__ node_emb, const float* __restrict__ ind_emb,
    const float* __restrict__ outd_emb,
    float* __restrict__ x, u16* __restrict__ xb)
{
  embed_body(blockIdx.x, node_type, nif, in_deg, out_deg, node_emb, ind_emb, outd_emb, x, xb);
}

// ---------------- spatial_pos transpose (fallback path only)
__global__ void spT_kernel(const int* __restrict__ sp, int* __restrict__ spT)
{
  __shared__ int tile[32][33];
  const int b = blockIdx.z;
  const int n0 = blockIdx.y * 32, m0 = blockIdx.x * 32;
  const int tx = threadIdx.x, ty = threadIdx.y;
  for (int i = ty; i < 32; i += 8)
    tile[i][tx] = sp[((size_t)b*Nn + n0 + i)*Nn + m0 + tx];
  __syncthreads();
  for (int i = ty; i < 32; i += 8)
    spT[((size_t)b*Nn + m0 + i)*Nn + n0 + tx] = tile[tx][i];
}

// ---------------- bias_pre body, tt-PAIRED chunk layout, INLINE transpose
// (reads sp columns directly; sp = 2.3MB -> L2-resident)
__device__ __forceinline__ void biaspre_body(
    int bid2, char* smemRaw,
    const float* __restrict__ atb, const int* __restrict__ sp,
    const float* __restrict__ sp_emb, const float* __restrict__ sp_emb_rev,
    u16* __restrict__ biasb)
{
  float* spc  = (float*)smemRaw;
  float* sprc = spc + 512;
  const int bx = bid2 % 24, h = (bid2 / 24) % Hh, b = bid2 / (24 * Hh);
  const int t = threadIdx.x;
  for (int i = t; i < 512; i += 256) {
    spc[i]  = sp_emb[(size_t)i*Hh + h];
    sprc[i] = sp_emb_rev[(size_t)i*Hh + h];
  }
  __syncthreads();
  const int qi = t >> 4;                 // 0..15 (q lane)
  const int ml = (t & 15) << 2;          // m within 64-group, multiple of 4
  const int qrow = bx*16 + qi;
  const size_t rowb = ((size_t)b*Nn + qrow)*Nn;
  u16* outb = biasb + ((size_t)(b*Hh + h)*24 + bx)*24*256;
  #pragma unroll
  for (int mg = 0; mg < 6; ++mg) {
    const int m = mg*64 + ml;
    float4 a4 = *(const float4*)(atb + rowb + m);
    int4  s4 = *(const int4*)(sp  + rowb + m);
    int4  t4;                              // spT[b][qrow][m+j] = sp[b][m+j][qrow]
    t4.x = sp[((size_t)b*Nn + m + 0)*Nn + qrow];
    t4.y = sp[((size_t)b*Nn + m + 1)*Nn + qrow];
    t4.z = sp[((size_t)b*Nn + m + 2)*Nn + qrow];
    t4.w = sp[((size_t)b*Nn + m + 3)*Nn + qrow];
    const int tt = m >> 4, hi2 = (m >> 2) & 3;
    uint2 u;
    u.x = pkcvt(a4.x + spc[s4.x] + sprc[t4.x], a4.y + spc[s4.y] + sprc[t4.y]);
    u.y = pkcvt(a4.z + spc[s4.z] + sprc[t4.z], a4.w + spc[s4.w] + sprc[t4.w]);
    *(uint2*)(outb + (tt >> 1)*512 + (hi2*16 + qi)*8 + (tt & 1)*4) = u;
  }
}

// ---------------- wconv body (shared): tid in [0,1728)
__device__ __forceinline__ void wconv_body(
    int tid, int layer, char* smemRaw,
    const float* Wq, const float* Wk, const float* Wv,
    const float* Wo, const float* W1, const float* W2, u16* slot)
{
  float (*tile)[65] = (float(*)[65])smemRaw;
  const float* src; u16* dst; int Ns, Ks;
  if (tid < 432)       { int seg = tid / 144; tid -= seg*144;
                         src = (seg==0?Wq:(seg==1?Wk:Wv)) + (size_t)layer*Ee*Ee;
                         dst = slot + (size_t)seg*589824; Ns = 768; Ks = 768; }
  else if (tid < 576)  { tid -= 432; src = Wo + (size_t)layer*Ee*Ee; dst = slot + 1769472; Ns = 768;  Ks = 768; }
  else if (tid < 1152) { tid -= 576; src = W1 + (size_t)layer*Ee*Ff; dst = slot + 2359296; Ns = 3072; Ks = 768; }
  else                 { tid -= 1152; src = W2 + (size_t)layer*Ff*Ee; dst = slot + 4718592; Ns = 768; Ks = 3072; }
  const int tc = Ns >> 6;
  const int tk = tid / tc, tn = tid % tc;
  const int t = threadIdx.x;
  #pragma unroll
  for (int i = 0; i < 4; ++i) {
    const int id = t + i*256;
    const int r = id >> 4, c = (id & 15) << 2;
    float4 v = *(const float4*)(src + (size_t)(tk*64 + r)*Ns + tn*64 + c);
    tile[r][c+0] = v.x; tile[r][c+1] = v.y; tile[r][c+2] = v.z; tile[r][c+3] = v.w;
  }
  __syncthreads();
  #pragma unroll
  for (int i = 0; i < 2; ++i) {
    const int ch = t + i*256;
    const int n = ch >> 3, kc = (ch & 7) << 3;
    uint4 u;
    u.x = pkcvt(tile[kc+0][n], tile[kc+1][n]);
    u.y = pkcvt(tile[kc+2][n], tile[kc+3][n]);
    u.z = pkcvt(tile[kc+4][n], tile[kc+5][n]);
    u.w = pkcvt(tile[kc+6][n], tile[kc+7][n]);
    *(uint4*)(dst + (size_t)(tn*64 + n)*Ks + tk*64 + kc) = u;
  }
}

__global__ __launch_bounds__(256) void wconv_kernel(
    const float* __restrict__ Wq, const float* __restrict__ Wk, const float* __restrict__ Wv,
    const float* __restrict__ Wo, const float* __restrict__ W1, const float* __restrict__ W2,
    int layer, u16* __restrict__ slot)
{
  __shared__ __align__(16) char smem[16640];
  wconv_body(blockIdx.x, layer, smem, Wq, Wk, Wv, Wo, W1, W2, slot);
}

// ---------------- FUSED upfront: embed (0..1535) | wconv l0 (1536..3263) | bias_pre (3264..6335)
__global__ __launch_bounds__(256) void prep_kernel(
    const int* __restrict__ node_type, const float* __restrict__ nif,
    const int* __restrict__ in_deg, const int* __restrict__ out_deg,
    const float* __restrict__ node_emb, const float* __restrict__ ind_emb,
    const float* __restrict__ outd_emb,
    float* __restrict__ x, u16* __restrict__ xb,
    const float* __restrict__ Wq, const float* __restrict__ Wk, const float* __restrict__ Wv,
    const float* __restrict__ Wo, const float* __restrict__ W1, const float* __restrict__ W2,
    u16* __restrict__ slot0,
    const float* __restrict__ atb, const int* __restrict__ sp,
    const float* __restrict__ sp_emb, const float* __restrict__ sp_emb_rev,
    u16* __restrict__ biasb)
{
  __shared__ __align__(16) char smem[16640];
  const int bid = blockIdx.x;
  if (bid < 1536) {
    embed_body(bid, node_type, nif, in_deg, out_deg, node_emb, ind_emb, outd_emb, x, xb);
  } else if (bid < 3264) {
    wconv_body(bid - 1536, 0, smem, Wq, Wk, Wv, Wo, W1, W2, slot0);
  } else {
    biaspre_body(bid - 3264, smem, atb, sp, sp_emb, sp_emb_rev, biasb);
  }
}

// ---------------- 128x64-tile GEMM, BK=64, counted-vmcnt 2-barrier pipeline, XCD-swizzled
// EPI 0: qkv fused bias (Q scaled) -> bf16 out ld 2304
// EPI 1: f32 partial out ld 768 (bias only on z==0)
// EPI 2: gelu -> bf16 out ld 3072
template<int EPI>
__device__ __forceinline__ void gemm_body(
    char* smemRaw, int bx0, int by0, int gx, int nwg, int zz,
    const u16* __restrict__ A, const u16* __restrict__ Bw,
    const float* __restrict__ b0, const float* __restrict__ b1, const float* __restrict__ b2,
    int Kfull, int Kc, float scaleQ,
    float* __restrict__ outF, u16* __restrict__ outB)
{
  u16 (*As)[128][64] = (u16(*)[128][64])smemRaw;            // 2 x 16KB
  u16 (*Bs)[64][64]  = (u16(*)[64][64])(smemRaw + 32768);   // 2 x 8KB
  const int t = threadIdx.x, lane = t & 63, wave = t >> 6;
  int bx = bx0, by = by0;
  { // XCD swizzle (nwg always divisible by 8)
    const int bid = bx + gx * by;
    const int cpx = nwg >> 3;
    const int s = (bid & 7) * cpx + (bid >> 3);
    bx = s % gx; by = s / gx;
  }
  const int m0 = bx * 128, n0 = by * 64;
  const int k0 = zz * Kc;
  const int wm = wave >> 1, wn = wave & 1;
  const int ql = lane & 15, hi = lane >> 4;
  const int nk = Kc >> 6;
  const int sr = t >> 3;
  const int sslot = (t & 7) ^ (sr & 7);
  const size_t aoff = (size_t)(m0 + sr)*Kfull + k0 + (sslot << 3);
  const size_t boff = (size_t)(n0 + sr)*Kfull + k0 + (sslot << 3);
  const size_t rstep = (size_t)32 * Kfull;

  int aro[4][2], bro[2][2];
  #pragma unroll
  for (int ks = 0; ks < 2; ++ks) {
    const int kb = (((ks<<2) + hi) ^ (ql & 7)) << 4;
    #pragma unroll
    for (int f = 0; f < 4; ++f) aro[f][ks] = (wm*64 + f*16 + ql)*128 + kb;
    #pragma unroll
    for (int f = 0; f < 2; ++f) bro[f][ks] = (wn*32 + f*16 + ql)*128 + kb;
  }

  f32x4 acc[4][2];
  #pragma unroll
  for (int a = 0; a < 4; ++a)
    #pragma unroll
    for (int c = 0; c < 2; ++c) acc[a][c] = (f32x4){0.f,0.f,0.f,0.f};

  #pragma unroll
  for (int i = 0; i < 4; ++i)
    gload_lds16(A + aoff + i*rstep, (char*)&As[0][0][0] + i*4096 + t*16);
  #pragma unroll
  for (int i = 0; i < 2; ++i)
    gload_lds16(Bw + boff + i*rstep, (char*)&Bs[0][0][0] + i*4096 + t*16);

  for (int kt = 0; kt < nk; ++kt) {
    const int cur = kt & 1, nxt = cur ^ 1;
    const bool pre = (kt + 1 < nk);
    if (pre) {
      const size_t kk = (size_t)(kt + 1) << 6;
      #pragma unroll
      for (int i = 0; i < 4; ++i)
        gload_lds16(A + aoff + kk + i*rstep, (char*)&As[nxt][0][0] + i*4096 + t*16);
      #pragma unroll
      for (int i = 0; i < 2; ++i)
        gload_lds16(Bw + boff + kk + i*rstep, (char*)&Bs[nxt][0][0] + i*4096 + t*16);
      asm volatile("s_waitcnt vmcnt(6)" ::: "memory");   // tile kt landed; kt+1 in flight
    } else {
      asm volatile("s_waitcnt vmcnt(0)" ::: "memory");
    }
    __builtin_amdgcn_s_barrier();            // B1
    __builtin_amdgcn_sched_barrier(0);

    const char* aBase = (const char*)&As[cur][0][0];
    const char* bBase = (const char*)&Bs[cur][0][0];
    bf16x8 af[4][2], bf[2][2];
    #pragma unroll
    for (int f = 0; f < 4; ++f)
      #pragma unroll
      for (int ks = 0; ks < 2; ++ks)
        af[f][ks] = *(const bf16x8*)(aBase + aro[f][ks]);
    #pragma unroll
    for (int f = 0; f < 2; ++f)
      #pragma unroll
      for (int ks = 0; ks < 2; ++ks)
        bf[f][ks] = *(const bf16x8*)(bBase + bro[f][ks]);
    #pragma unroll
    for (int ks = 0; ks < 2; ++ks)
      #pragma unroll
      for (int fm = 0; fm < 4; ++fm)
        #pragma unroll
        for (int fn = 0; fn < 2; ++fn)
          acc[fm][fn] = __builtin_amdgcn_mfma_f32_16x16x32_bf16(af[fm][ks], bf[fn][ks], acc[fm][fn], 0, 0, 0);
    if (pre) {
      __builtin_amdgcn_sched_barrier(0);
      __builtin_amdgcn_s_barrier();          // B2: cur reads drained before overwrite
    }
  }

  #pragma unroll
  for (int fm = 0; fm < 4; ++fm) {
    const int rowb = m0 + wm*64 + fm*16 + hi*4;
    #pragma unroll
    for (int fn = 0; fn < 2; ++fn) {
      const int gcol = n0 + wn*32 + fn*16 + ql;
      float bv, scale = 1.0f;
      if (EPI == 0) {
        const int seg = gcol / 768;
        const int cw = gcol - seg*768;
        bv = (seg == 0) ? b0[cw] : ((seg == 1) ? b1[cw] : b2[cw]);
        if (seg == 0) scale = scaleQ;
      } else if (EPI == 1) {
        bv = (zz == 0) ? b0[gcol] : 0.0f;
      } else {
        bv = b0[gcol];
      }
      f32x4 v = acc[fm][fn];
      #pragma unroll
      for (int j = 0; j < 4; ++j) {
        float val = (v[j] + bv) * scale;
        if (EPI == 0) {
          outB[(size_t)(rowb + j) * 2304 + gcol] = f2b(val);
        } else if (EPI == 1) {
          outF[(size_t)zz * (Mm*768) + (size_t)(rowb + j) * 768 + gcol] = val;
        } else {
          float arg = 0.7978845608028654f * (val + 0.044715f * val * val * val);
          float e = __expf(2.0f * arg);
          float g = 0.5f * val * (2.0f - 2.0f / (e + 1.0f));
          outB[(size_t)(rowb + j) * 3072 + gcol] = f2b(g);
        }
      }
    }
  }
}

template<int EPI>
__global__ __launch_bounds__(256) void gemm3_kernel(
    const u16* __restrict__ A, const u16* __restrict__ Bw,
    const float* __restrict__ b0, const float* __restrict__ b1, const float* __restrict__ b2,
    int Kfull, int Kc, float scaleQ,
    float* __restrict__ outF, u16* __restrict__ outB)
{
  __shared__ __align__(16) char smem[49152];
  gemm_body<EPI>(smem, blockIdx.x, blockIdx.y, gridDim.x, gridDim.x*gridDim.y,
                 blockIdx.z, A, Bw, b0, b1, b2, Kfull, Kc, scaleQ, outF, outB);
}

// ---------------- FUSED: FFN2 GEMM (blocks 0..575, grid (12,12,4) flattened) +
// wconv of NEXT layer's weights into the other slot (blocks 576..2303).
__global__ __launch_bounds__(256) void ffn2w_kernel(
    const u16* __restrict__ A, const u16* __restrict__ w2T,
    const float* __restrict__ b2v, float* __restrict__ outF,
    const float* __restrict__ Wq, const float* __restrict__ Wk, const float* __restrict__ Wv,
    const float* __restrict__ Wo, const float* __restrict__ W1, const float* __restrict__ W2,
    int layerNext, u16* __restrict__ slotNext, int doW)
{
  __shared__ __align__(16) char smem[49152];
  const int bid = blockIdx.x;
  if (bid < 576) {
    const int zz = bid / 144, r = bid - zz*144;
    gemm_body<1>(smem, r % 12, r / 12, 12, 144, zz,
                 A, w2T, b2v, b2v, b2v, 3072, 768, 1.0f, outF, nullptr);
  } else if (doW) {
    wconv_body(bid - 576, layerNext, smem, Wq, Wk, Wv, Wo, W1, W2, slotNext);
  }
}

// ---------------- MFMA attention: block = (b, h, pair of 64-q-row tiles)
template<int PREBIAS>
__global__ __launch_bounds__(256) void attn2_kernel(
    const u16* __restrict__ qkv,         // [1536][2304] bf16 q|k|v (q pre-scaled)
    const u16* __restrict__ biasb,       // tt-paired chunk layout (PREBIAS=1)
    const float* __restrict__ atb, const int* __restrict__ sp, const int* __restrict__ spT,
    const float* __restrict__ sp_emb, const float* __restrict__ sp_emb_rev,
    u16* __restrict__ ab)                // [1536][768] bf16
{
  __shared__ __align__(16) u16 Kt[384][32];   // [m][d(24)+pad]
  __shared__ __align__(16) u16 Vt[32][392];   // [d(24)+pad][m] transposed
  __shared__ __align__(16) u16 Qt[128][32];   // both q-tiles
  __shared__ __align__(16) u16 Pw[4][16][32]; // per-wave P chunk
  __shared__ float spc[512], sprc[512];
  const int bid = blockIdx.x;
  const int pair = bid % 3;
  const int h = (bid / 3) % Hh;
  const int b = bid / (3 * Hh);
  const int t = threadIdx.x, lane = t & 63, wave = t >> 6;
  const int ql = lane & 15, hi = lane >> 4;

  for (int idx = t; idx < 384*3; idx += 256) {         // K + V^T staging, 16B loads
    const int m = idx / 3, c = idx - m*3;
    const u16* base = qkv + ((size_t)m*Bb + b)*2304 + h*24 + c*8;
    uint4 kk = *(const uint4*)(base + 768);
    uint4 vv = *(const uint4*)(base + 1536);
    *(uint4*)&Kt[m][c*8] = kk;
    Vt[c*8+0][m] = (u16)(vv.x & 0xffffu); Vt[c*8+1][m] = (u16)(vv.x >> 16);
    Vt[c*8+2][m] = (u16)(vv.y & 0xffffu); Vt[c*8+3][m] = (u16)(vv.y >> 16);
    Vt[c*8+4][m] = (u16)(vv.z & 0xffffu); Vt[c*8+5][m] = (u16)(vv.z >> 16);
    Vt[c*8+6][m] = (u16)(vv.w & 0xffffu); Vt[c*8+7][m] = (u16)(vv.w >> 16);
  }
  for (int idx = t; idx < 384*2; idx += 256)           // K d-pad
    *(uint2*)&Kt[idx>>1][24 + (idx&1)*4] = make_uint2(0u, 0u);
  for (int idx = t; idx < 8*196; idx += 256)           // V^T d-pad rows
    *(unsigned*)((char*)&Vt[24][0] + idx*4) = 0u;
  for (int idx = t; idx < 128*3; idx += 256) {         // Q: both tiles upfront, 16B loads
    const int qr = idx / 3, c = idx - qr*3;
    const u16* base = qkv + ((size_t)(pair*128 + qr)*Bb + b)*2304 + h*24 + c*8;
    *(uint4*)&Qt[qr][c*8] = *(const uint4*)base;
  }
  for (int idx = t; idx < 128*2; idx += 256)           // Q d-pad
    *(uint2*)&Qt[idx>>1][24 + (idx&1)*4] = make_uint2(0u, 0u);
  if (!PREBIAS) {
    for (int i = t; i < 512; i += 256) {
      spc[i]  = sp_emb[(size_t)i*Hh + h];
      sprc[i] = sp_emb_rev[(size_t)i*Hh + h];
    }
  }
  __syncthreads();   // all staging done; loop below is barrier-free

  for (int qi = 0; qi < 2; ++qi) {
    const int ntile = pair*2 + qi;
    const int q0 = ntile*64 + wave*16;
    const int q = q0 + ql;
    const bf16x8 qf = *(const bf16x8*)&Qt[qi*64 + wave*16 + ql][hi*8];

    f32x4 f[24];
    const size_t crow = ((size_t)b*Nn + q)*Nn;
    if (PREBIAS) {
      const u16* bp = biasb + (((size_t)(b*Hh + h)*24 + ntile*4 + wave)*24)*256 + lane*8;
      #pragma unroll
      for (int tt2 = 0; tt2 < 12; ++tt2) {
        uint4 bb = *(const uint4*)(bp + tt2*512);
        {
          bf16x8 kf = *(const bf16x8*)&Kt[(2*tt2)*16 + ql][hi*8];
          f32x4 z = (f32x4){0.f,0.f,0.f,0.f};
          f32x4 s = __builtin_amdgcn_mfma_f32_16x16x32_bf16(kf, qf, z, 0, 0, 0);
          s[0] += b2f((u16)(bb.x & 0xffffu)); s[1] += b2f((u16)(bb.x >> 16));
          s[2] += b2f((u16)(bb.y & 0xffffu)); s[3] += b2f((u16)(bb.y >> 16));
          f[2*tt2] = s;
        }
        {
          bf16x8 kf = *(const bf16x8*)&Kt[(2*tt2+1)*16 + ql][hi*8];
          f32x4 z = (f32x4){0.f,0.f,0.f,0.f};
          f32x4 s = __builtin_amdgcn_mfma_f32_16x16x32_bf16(kf, qf, z, 0, 0, 0);
          s[0] += b2f((u16)(bb.z & 0xffffu)); s[1] += b2f((u16)(bb.z >> 16));
          s[2] += b2f((u16)(bb.w & 0xffffu)); s[3] += b2f((u16)(bb.w >> 16));
          f[2*tt2+1] = s;
        }
      }
    } else {
      #pragma unroll
      for (int tt = 0; tt < 24; ++tt) {
        bf16x8 kf = *(const bf16x8*)&Kt[tt*16 + ql][hi*8];
        f32x4 z = (f32x4){0.f,0.f,0.f,0.f};
        f32x4 s = __builtin_amdgcn_mfma_f32_16x16x32_bf16(kf, qf, z, 0, 0, 0);
        const int off = tt*16 + hi*4;
        int4 s4 = *(const int4*)(sp + crow + off);
        int4 t4 = *(const int4*)(spT + crow + off);
        float4 a4 = *(const float4*)(atb + crow + off);
        s[0] += a4.x + spc[s4.x] + sprc[t4.x];
        s[1] += a4.y + spc[s4.y] + sprc[t4.y];
        s[2] += a4.z + spc[s4.z] + sprc[t4.z];
        s[3] += a4.w + spc[s4.w] + sprc[t4.w];
        f[tt] = s;
      }
    }

    float mx = -3.0e38f;
    #pragma unroll
    for (int tt = 0; tt < 24; ++tt)
      mx = fmaxf(mx, fmaxf(fmaxf(f[tt][0], f[tt][1]), fmaxf(f[tt][2], f[tt][3])));
    mx = fmaxf(mx, __shfl_xor(mx, 16, 64));
    mx = fmaxf(mx, __shfl_xor(mx, 32, 64));
    float sum = 0.f;
    #pragma unroll
    for (int tt = 0; tt < 24; ++tt) {
      #pragma unroll
      for (int j = 0; j < 4; ++j) { f[tt][j] = __expf(f[tt][j] - mx); sum += f[tt][j]; }
    }
    sum += __shfl_xor(sum, 16, 64);
    sum += __shfl_xor(sum, 32, 64);
    const float inv = 1.0f / sum;

    f32x4 o0 = (f32x4){0.f,0.f,0.f,0.f}, o1 = (f32x4){0.f,0.f,0.f,0.f};
    char* prow = (char*)&Pw[wave][ql][0];
    const int swz = (ql & 3) << 4;
    #pragma unroll
    for (int c = 0; c < 12; ++c) {
      unsigned w0 = pkcvt(f[2*c][0],   f[2*c][1]);
      unsigned w1 = pkcvt(f[2*c][2],   f[2*c][3]);
      unsigned w2 = pkcvt(f[2*c+1][0], f[2*c+1][1]);
      unsigned w3 = pkcvt(f[2*c+1][2], f[2*c+1][3]);
      *(unsigned*)(prow + (((hi*8)      ) ^ swz)) = w0;
      *(unsigned*)(prow + (((hi*8) +  4) ^ swz)) = w1;
      *(unsigned*)(prow + (((hi*8) + 32) ^ swz)) = w2;
      *(unsigned*)(prow + (((hi*8) + 36) ^ swz)) = w3;
      bf16x8 a = *(const bf16x8*)(prow + ((hi*16) ^ swz));
      bf16x8 v0 = *(const bf16x8*)&Vt[ql][c*32 + hi*8];
      bf16x8 v1 = *(const bf16x8*)&Vt[16 + ql][c*32 + hi*8];
      o0 = __builtin_amdgcn_mfma_f32_16x16x32_bf16(a, v0, o0, 0, 0, 0);
      o1 = __builtin_amdgcn_mfma_f32_16x16x32_bf16(a, v1, o1, 0, 0, 0);
    }

    #pragma unroll
    for (int j = 0; j < 4; ++j) {
      float invj = __shfl(inv, hi*4 + j, 64);
      const int qg = q0 + hi*4 + j;
      u16* orow = ab + ((size_t)qg*Bb + b)*Ee + h*24;
      orow[ql] = f2b(o0[j] * invj);
      if (ql < 8) orow[16 + ql] = f2b(o1[j] * invj);
    }
  }
}

// ---------------- residual + LayerNorm: wave-per-row, no block barriers, float4 loads
template<int NP>
__global__ __launch_bounds__(256) void ln_kernel(
    const float* __restrict__ xin, const float* __restrict__ delta,
    const float* __restrict__ gamma, const float* __restrict__ beta,
    float* __restrict__ xout, u16* __restrict__ xb)
{
  const int wave = threadIdx.x >> 6, lane = threadIdx.x & 63;
  const int r = blockIdx.x * 4 + wave;
  const size_t base = (size_t)r * Ee;
  const int c0 = lane * 12;
  float v[12];
  #pragma unroll
  for (int i = 0; i < 3; ++i) {
    float4 xv = *(const float4*)(xin + base + c0 + i*4);
    v[i*4+0] = xv.x; v[i*4+1] = xv.y; v[i*4+2] = xv.z; v[i*4+3] = xv.w;
  }
  #pragma unroll
  for (int p = 0; p < NP; ++p) {
    const float* dp = delta + (size_t)p*(Mm*768) + base + c0;
    #pragma unroll
    for (int i = 0; i < 3; ++i) {
      float4 dv = *(const float4*)(dp + i*4);
      v[i*4+0] += dv.x; v[i*4+1] += dv.y; v[i*4+2] += dv.z; v[i*4+3] += dv.w;
    }
  }
  float s = 0.f;
  #pragma unroll
  for (int i = 0; i < 12; ++i) s += v[i];
  #pragma unroll
  for (int off = 1; off < 64; off <<= 1) s += __shfl_xor(s, off, 64);
  const float mean = s * (1.0f / 768.0f);
  float qs = 0.f;
  #pragma unroll
  for (int i = 0; i < 12; ++i) { float d = v[i] - mean; qs += d * d; }
  #pragma unroll
  for (int off = 1; off < 64; off <<= 1) qs += __shfl_xor(qs, off, 64);
  const float rstd = rsqrtf(qs * (1.0f / 768.0f) + 1e-5f);
  float o[12];
  #pragma unroll
  for (int i = 0; i < 3; ++i) {
    float4 g4 = *(const float4*)(gamma + c0 + i*4);
    float4 b4 = *(const float4*)(beta + c0 + i*4);
    o[i*4+0] = (v[i*4+0] - mean) * rstd * g4.x + b4.x;
    o[i*4+1] = (v[i*4+1] - mean) * rstd * g4.y + b4.y;
    o[i*4+2] = (v[i*4+2] - mean) * rstd * g4.z + b4.z;
    o[i*4+3] = (v[i*4+3] - mean) * rstd * g4.w + b4.w;
    *(float4*)(xout + base + c0 + i*4) = make_float4(o[i*4+0], o[i*4+1], o[i*4+2], o[i*4+3]);
  }
  #pragma unroll
  for (int i = 0; i < 3; ++i) {
    uint2 u;
    u.x = pkcvt(o[i*4+0], o[i*4+1]);
    u.y = pkcvt(o[i*4+2], o[i*4+3]);
    *(uint2*)(xb + base + c0 + i*4) = u;
  }
}

extern "C" void kernel_launch(void* const* d_in, const int* in_sizes, int n_in,
                              void* d_out, int out_size, void* d_ws, size_t ws_size,
                              hipStream_t stream) {
  const int*   node_type  = (const int*)d_in[0];
  const float* nif        = (const float*)d_in[1];
  const int*   in_deg     = (const int*)d_in[2];
  const int*   out_deg    = (const int*)d_in[3];
  const float* atb        = (const float*)d_in[4];
  const int*   sp         = (const int*)d_in[5];
  const float* node_emb   = (const float*)d_in[6];
  const float* ind_emb    = (const float*)d_in[7];
  const float* outd_emb   = (const float*)d_in[8];
  const float* sp_emb     = (const float*)d_in[9];
  const float* sp_emb_rev = (const float*)d_in[10];
  const float* Wq = (const float*)d_in[11]; const float* bq = (const float*)d_in[12];
  const float* Wk = (const float*)d_in[13]; const float* bk = (const float*)d_in[14];
  const float* Wv = (const float*)d_in[15]; const float* bv = (const float*)d_in[16];
  const float* Wo = (const float*)d_in[17]; const float* bo = (const float*)d_in[18];
  const float* W1 = (const float*)d_in[19]; const float* b1 = (const float*)d_in[20];
  const float* W2 = (const float*)d_in[21]; const float* b2 = (const float*)d_in[22];
  const float* ln1s = (const float*)d_in[23]; const float* ln1b = (const float*)d_in[24];
  const float* ln2s = (const float*)d_in[25]; const float* ln2b = (const float*)d_in[26];

  char* ws = (char*)d_ws;
  float* x      = (float*)(ws);                    //  4,718,592
  u16*   xb     = (u16*)(ws +  4718592);           //  2,359,296
  u16*   qkvb16 = (u16*)(ws +  7077888);           //  7,077,888
  u16*   abuf   = (u16*)(ws + 14155776);           //  2,359,296
  u16*   hb     = (u16*)(ws + 16515072);           //  9,437,184
  float* obufP  = (float*)(ws + 25952256);         // 18,874,368 (4 partials)
  int*   spTb   = (int*)(ws + 44826624);           //  2,359,296
  u16*   biasb  = (u16*)(ws + 47185920);           // 37,748,736 -> 84,934,656
  u16*   wTs0   = (u16*)(ws + 84934656);           // 14,155,776
  u16*   wTs1   = (u16*)(ws + 99090432);           // 14,155,776 -> 113,246,208
  const bool useBias = ws_size >= 113246208ull;
  u16* slots[2] = { wTs0, wTs1 };

  if (useBias) {
    // fused upfront: embed | wconv(l0) | bias_pre (inline transpose)
    prep_kernel<<<6336, 256, 0, stream>>>(node_type, nif, in_deg, out_deg,
                                          node_emb, ind_emb, outd_emb, x, xb,
                                          Wq, Wk, Wv, Wo, W1, W2, slots[0],
                                          atb, sp, sp_emb, sp_emb_rev, biasb);
  } else {
    embed_kernel<<<Mm, 256, 0, stream>>>(node_type, nif, in_deg, out_deg,
                                         node_emb, ind_emb, outd_emb, x, xb);
    spT_kernel<<<dim3(12, 12, 4), dim3(32, 8), 0, stream>>>(sp, spTb);
    wconv_kernel<<<1728, 256, 0, stream>>>(Wq, Wk, Wv, Wo, W1, W2, 0, slots[0]);
  }

  const float scaleQ = 0.2041241452319315f;  // 24^-0.5

  for (int l = 0; l < Ll; ++l) {
    const float *bql = bq + (size_t)l*Ee, *bkl = bk + (size_t)l*Ee, *bvl = bv + (size_t)l*Ee;
    const float *bol = bo + (size_t)l*Ee;
    const float *b1l = b1 + (size_t)l*Ff, *b2l = b2 + (size_t)l*Ee;

    u16* slot = slots[l & 1];
    u16* slotN = slots[(l + 1) & 1];
    const u16* qkvT = slot;
    const u16* woT  = slot + 1769472;
    const u16* w1T  = slot + 2359296;
    const u16* w2T  = slot + 4718592;

    // QKV: [1536,768] @ [2304,768]^T -> bf16 [1536][2304]
    gemm3_kernel<0><<<dim3(12, 36), 256, 0, stream>>>(xb, qkvT, bql, bkl, bvl,
                                                      768, 768, scaleQ, nullptr, qkvb16);
    if (useBias)
      attn2_kernel<1><<<384, 256, 0, stream>>>(qkvb16, biasb, atb, sp, spTb,
                                               sp_emb, sp_emb_rev, abuf);
    else
      attn2_kernel<0><<<384, 256, 0, stream>>>(qkvb16, nullptr, atb, sp, spTb,
                                               sp_emb, sp_emb_rev, abuf);
    // O-proj: split-K 2 -> partials
    gemm3_kernel<1><<<dim3(12, 12, 2), 256, 0, stream>>>(abuf, woT, bol, bol, bol,
                                                         768, 384, 1.0f, obufP, nullptr);
    ln_kernel<2><<<Mm/4, 256, 0, stream>>>(x, obufP, ln1s + (size_t)l*Ee, ln1b + (size_t)l*Ee, x, xb);
    // FFN1 + gelu -> bf16 hidden
    gemm3_kernel<2><<<dim3(12, 48), 256, 0, stream>>>(xb, w1T, b1l, b1l, b1l,
                                                      768, 768, 1.0f, nullptr, hb);
    // FFN2 split-K 4 (blocks 0..575)  FUSED with  wconv(layer l+1) -> other slot
    ffn2w_kernel<<<2304, 256, 0, stream>>>(hb, w2T, b2l, obufP,
                                           Wq, Wk, Wv, Wo, W1, W2,
                                           l + 1, slotN, (l + 1 < Ll) ? 1 : 0);
    float* xdst = (l == Ll - 1) ? (float*)d_out : x;
    ln_kernel<4><<<Mm/4, 256, 0, stream>>>(x, obufP, ln2s + (size_t)l*Ee, ln2b + (size_t)l*Ee, xdst, xb);
  }
}

// Round 20
// 1181.883 us; speedup vs baseline: 1.0115x; 1.0115x over previous
//
#include <hip/hip_runtime.h>
#include <hip/hip_bf16.h>

#define Bb 4
#define Nn 384
#define Ee 768
#define Hh 32
#define Ff 3072
#define Ll 12
#define Ss 512
#define Mm (Nn*Bb)   // 1536 tokens

typedef __attribute__((ext_vector_type(8))) short bf16x8;
typedef __attribute__((ext_vector_type(4))) float f32x4;
typedef unsigned short u16;

__device__ __forceinline__ u16 f2b(float f) {
  union { float f; unsigned int i; } c; c.f = f;
  unsigned int x = c.i;
  return (u16)((x + 0x7fffu + ((x >> 16) & 1u)) >> 16); // RNE
}
__device__ __forceinline__ float b2f(u16 u) {
  union { unsigned int i; float f; } c; c.i = ((unsigned int)u) << 16; return c.f;
}
__device__ __forceinline__ unsigned pkcvt(float lo, float hi) {
  unsigned r;
  asm("v_cvt_pk_bf16_f32 %0, %1, %2" : "=v"(r) : "v"(lo), "v"(hi));
  return r;
}
__device__ __forceinline__ void gload_lds16(const void* g, void* l) {
  __builtin_amdgcn_global_load_lds((__attribute__((address_space(1))) void*)(g),
                                   (__attribute__((address_space(3))) void*)(l), 16, 0, 0);
}

// ---------------- embed body
__device__ __forceinline__ void embed_body(
    int r, const int* __restrict__ node_type, const float* __restrict__ nif,
    const int* __restrict__ in_deg, const int* __restrict__ out_deg,
    const float* __restrict__ node_emb, const float* __restrict__ ind_emb,
    const float* __restrict__ outd_emb,
    float* __restrict__ x, u16* __restrict__ xb)
{
  const int n = r / Bb, b = r % Bb;
  const int nt  = node_type[b*Nn + n];
  const int idg = in_deg[b*Nn + n];
  const int odg = out_deg[b*Nn + n];
  for (int c = threadIdx.x; c < Ee; c += 256) {
    float val = node_emb[(size_t)nt*Ee + c] + ind_emb[(size_t)idg*Ee + c]
              + outd_emb[(size_t)odg*Ee + c] + nif[((size_t)b*Nn + n)*Ee + c];
    x[(size_t)r*Ee + c] = val;
    xb[(size_t)r*Ee + c] = f2b(val);
  }
}

// ---------------- spT body (32x33 LDS tile transpose, 256 1-D threads): bid in [0,576)
__device__ __forceinline__ void spT_body(
    int bid, char* smemRaw, const int* __restrict__ sp, int* __restrict__ spT)
{
  int (*tile)[33] = (int(*)[33])smemRaw;
  const int b = bid / 144, rem = bid % 144;
  const int m0 = (rem % 12) * 32, n0 = (rem / 12) * 32;
  const int tx = threadIdx.x & 31, ty = threadIdx.x >> 5;
  for (int i = ty; i < 32; i += 8)
    tile[i][tx] = sp[((size_t)b*Nn + n0 + i)*Nn + m0 + tx];
  __syncthreads();
  for (int i = ty; i < 32; i += 8)
    spT[((size_t)b*Nn + m0 + i)*Nn + n0 + tx] = tile[tx][i];
}

// ---------------- wconv body (shared): tid in [0,1728)
__device__ __forceinline__ void wconv_body(
    int tid, int layer, char* smemRaw,
    const float* Wq, const float* Wk, const float* Wv,
    const float* Wo, const float* W1, const float* W2, u16* slot)
{
  float (*tile)[65] = (float(*)[65])smemRaw;
  const float* src; u16* dst; int Ns, Ks;
  if (tid < 432)       { int seg = tid / 144; tid -= seg*144;
                         src = (seg==0?Wq:(seg==1?Wk:Wv)) + (size_t)layer*Ee*Ee;
                         dst = slot + (size_t)seg*589824; Ns = 768; Ks = 768; }
  else if (tid < 576)  { tid -= 432; src = Wo + (size_t)layer*Ee*Ee; dst = slot + 1769472; Ns = 768;  Ks = 768; }
  else if (tid < 1152) { tid -= 576; src = W1 + (size_t)layer*Ee*Ff; dst = slot + 2359296; Ns = 3072; Ks = 768; }
  else                 { tid -= 1152; src = W2 + (size_t)layer*Ff*Ee; dst = slot + 4718592; Ns = 768; Ks = 3072; }
  const int tc = Ns >> 6;
  const int tk = tid / tc, tn = tid % tc;
  const int t = threadIdx.x;
  #pragma unroll
  for (int i = 0; i < 4; ++i) {
    const int id = t + i*256;
    const int r = id >> 4, c = (id & 15) << 2;
    float4 v = *(const float4*)(src + (size_t)(tk*64 + r)*Ns + tn*64 + c);
    tile[r][c+0] = v.x; tile[r][c+1] = v.y; tile[r][c+2] = v.z; tile[r][c+3] = v.w;
  }
  __syncthreads();
  #pragma unroll
  for (int i = 0; i < 2; ++i) {
    const int ch = t + i*256;
    const int n = ch >> 3, kc = (ch & 7) << 3;
    uint4 u;
    u.x = pkcvt(tile[kc+0][n], tile[kc+1][n]);
    u.y = pkcvt(tile[kc+2][n], tile[kc+3][n]);
    u.z = pkcvt(tile[kc+4][n], tile[kc+5][n]);
    u.w = pkcvt(tile[kc+6][n], tile[kc+7][n]);
    *(uint4*)(dst + (size_t)(tn*64 + n)*Ks + tk*64 + kc) = u;
  }
}

__global__ __launch_bounds__(256) void wconv_kernel(
    const float* __restrict__ Wq, const float* __restrict__ Wk, const float* __restrict__ Wv,
    const float* __restrict__ Wo, const float* __restrict__ W1, const float* __restrict__ W2,
    int layer, u16* __restrict__ slot)
{
  __shared__ __align__(16) char smem[16640];
  wconv_body(blockIdx.x, layer, smem, Wq, Wk, Wv, Wo, W1, W2, slot);
}

// ---------------- FUSED upfront: embed (0..1535) | spT (1536..2111) | wconv l0 (2112..3839)
__global__ __launch_bounds__(256) void prep_kernel(
    const int* __restrict__ node_type, const float* __restrict__ nif,
    const int* __restrict__ in_deg, const int* __restrict__ out_deg,
    const float* __restrict__ node_emb, const float* __restrict__ ind_emb,
    const float* __restrict__ outd_emb,
    float* __restrict__ x, u16* __restrict__ xb,
    const int* __restrict__ sp, int* __restrict__ spT,
    const float* __restrict__ Wq, const float* __restrict__ Wk, const float* __restrict__ Wv,
    const float* __restrict__ Wo, const float* __restrict__ W1, const float* __restrict__ W2,
    u16* __restrict__ slot0)
{
  __shared__ __align__(16) char smem[16640];
  const int bid = blockIdx.x;
  if (bid < 1536) {
    embed_body(bid, node_type, nif, in_deg, out_deg, node_emb, ind_emb, outd_emb, x, xb);
  } else if (bid < 2112) {
    spT_body(bid - 1536, smem, sp, spT);
  } else {
    wconv_body(bid - 2112, 0, smem, Wq, Wk, Wv, Wo, W1, W2, slot0);
  }
}

// ---------------- bias precompute (coalesced, spT-based), tt-PAIRED chunk layout
__global__ __launch_bounds__(256) void bias_pre_kernel(
    const float* __restrict__ atb, const int* __restrict__ sp, const int* __restrict__ spT,
    const float* __restrict__ sp_emb, const float* __restrict__ sp_emb_rev,
    u16* __restrict__ biasb)
{
  __shared__ float spc[512], sprc[512];
  const int bx = blockIdx.x, h = blockIdx.y, b = blockIdx.z;
  const int t = threadIdx.x;
  for (int i = t; i < 512; i += 256) {
    spc[i]  = sp_emb[(size_t)i*Hh + h];
    sprc[i] = sp_emb_rev[(size_t)i*Hh + h];
  }
  __syncthreads();
  const int qi = t >> 4;                 // 0..15 (q lane)
  const int ml = (t & 15) << 2;          // m within 64-group, multiple of 4
  const size_t rowb = ((size_t)b*Nn + bx*16 + qi)*Nn;
  u16* outb = biasb + ((size_t)(b*Hh + h)*24 + bx)*24*256;
  #pragma unroll
  for (int mg = 0; mg < 6; ++mg) {
    const int m = mg*64 + ml;
    float4 a4 = *(const float4*)(atb + rowb + m);
    int4  s4 = *(const int4*)(sp  + rowb + m);
    int4  t4 = *(const int4*)(spT + rowb + m);
    const int tt = m >> 4, hi2 = (m >> 2) & 3;
    uint2 u;
    u.x = pkcvt(a4.x + spc[s4.x] + sprc[t4.x], a4.y + spc[s4.y] + sprc[t4.y]);
    u.y = pkcvt(a4.z + spc[s4.z] + sprc[t4.z], a4.w + spc[s4.w] + sprc[t4.w]);
    *(uint2*)(outb + (tt >> 1)*512 + (hi2*16 + qi)*8 + (tt & 1)*4) = u;
  }
}

// ---------------- 128x64-tile GEMM, BK=64, counted-vmcnt 2-barrier pipeline, XCD-swizzled
// EPI 0: qkv fused bias (Q scaled) -> bf16 out ld 2304
// EPI 1: f32 partial out ld 768 (bias only on z==0)
// EPI 2: gelu -> bf16 out ld 3072
template<int EPI>
__device__ __forceinline__ void gemm_body(
    char* smemRaw, int bx0, int by0, int gx, int nwg, int zz,
    const u16* __restrict__ A, const u16* __restrict__ Bw,
    const float* __restrict__ b0, const float* __restrict__ b1, const float* __restrict__ b2,
    int Kfull, int Kc, float scaleQ,
    float* __restrict__ outF, u16* __restrict__ outB)
{
  u16 (*As)[128][64] = (u16(*)[128][64])smemRaw;            // 2 x 16KB
  u16 (*Bs)[64][64]  = (u16(*)[64][64])(smemRaw + 32768);   // 2 x 8KB
  const int t = threadIdx.x, lane = t & 63, wave = t >> 6;
  int bx = bx0, by = by0;
  { // XCD swizzle (nwg always divisible by 8)
    const int bid = bx + gx * by;
    const int cpx = nwg >> 3;
    const int s = (bid & 7) * cpx + (bid >> 3);
    bx = s % gx; by = s / gx;
  }
  const int m0 = bx * 128, n0 = by * 64;
  const int k0 = zz * Kc;
  const int wm = wave >> 1, wn = wave & 1;
  const int ql = lane & 15, hi = lane >> 4;
  const int nk = Kc >> 6;
  const int sr = t >> 3;
  const int sslot = (t & 7) ^ (sr & 7);
  const size_t aoff = (size_t)(m0 + sr)*Kfull + k0 + (sslot << 3);
  const size_t boff = (size_t)(n0 + sr)*Kfull + k0 + (sslot << 3);
  const size_t rstep = (size_t)32 * Kfull;

  int aro[4][2], bro[2][2];
  #pragma unroll
  for (int ks = 0; ks < 2; ++ks) {
    const int kb = (((ks<<2) + hi) ^ (ql & 7)) << 4;
    #pragma unroll
    for (int f = 0; f < 4; ++f) aro[f][ks] = (wm*64 + f*16 + ql)*128 + kb;
    #pragma unroll
    for (int f = 0; f < 2; ++f) bro[f][ks] = (wn*32 + f*16 + ql)*128 + kb;
  }

  f32x4 acc[4][2];
  #pragma unroll
  for (int a = 0; a < 4; ++a)
    #pragma unroll
    for (int c = 0; c < 2; ++c) acc[a][c] = (f32x4){0.f,0.f,0.f,0.f};

  #pragma unroll
  for (int i = 0; i < 4; ++i)
    gload_lds16(A + aoff + i*rstep, (char*)&As[0][0][0] + i*4096 + t*16);
  #pragma unroll
  for (int i = 0; i < 2; ++i)
    gload_lds16(Bw + boff + i*rstep, (char*)&Bs[0][0][0] + i*4096 + t*16);

  for (int kt = 0; kt < nk; ++kt) {
    const int cur = kt & 1, nxt = cur ^ 1;
    const bool pre = (kt + 1 < nk);
    if (pre) {
      const size_t kk = (size_t)(kt + 1) << 6;
      #pragma unroll
      for (int i = 0; i < 4; ++i)
        gload_lds16(A + aoff + kk + i*rstep, (char*)&As[nxt][0][0] + i*4096 + t*16);
      #pragma unroll
      for (int i = 0; i < 2; ++i)
        gload_lds16(Bw + boff + kk + i*rstep, (char*)&Bs[nxt][0][0] + i*4096 + t*16);
      asm volatile("s_waitcnt vmcnt(6)" ::: "memory");   // tile kt landed; kt+1 in flight
    } else {
      asm volatile("s_waitcnt vmcnt(0)" ::: "memory");
    }
    __builtin_amdgcn_s_barrier();            // B1
    __builtin_amdgcn_sched_barrier(0);

    const char* aBase = (const char*)&As[cur][0][0];
    const char* bBase = (const char*)&Bs[cur][0][0];
    bf16x8 af[4][2], bf[2][2];
    #pragma unroll
    for (int f = 0; f < 4; ++f)
      #pragma unroll
      for (int ks = 0; ks < 2; ++ks)
        af[f][ks] = *(const bf16x8*)(aBase + aro[f][ks]);
    #pragma unroll
    for (int f = 0; f < 2; ++f)
      #pragma unroll
      for (int ks = 0; ks < 2; ++ks)
        bf[f][ks] = *(const bf16x8*)(bBase + bro[f][ks]);
    #pragma unroll
    for (int ks = 0; ks < 2; ++ks)
      #pragma unroll
      for (int fm = 0; fm < 4; ++fm)
        #pragma unroll
        for (int fn = 0; fn < 2; ++fn)
          acc[fm][fn] = __builtin_amdgcn_mfma_f32_16x16x32_bf16(af[fm][ks], bf[fn][ks], acc[fm][fn], 0, 0, 0);
    if (pre) {
      __builtin_amdgcn_sched_barrier(0);
      __builtin_amdgcn_s_barrier();          // B2: cur reads drained before overwrite
    }
  }

  #pragma unroll
  for (int fm = 0; fm < 4; ++fm) {
    const int rowb = m0 + wm*64 + fm*16 + hi*4;
    #pragma unroll
    for (int fn = 0; fn < 2; ++fn) {
      const int gcol = n0 + wn*32 + fn*16 + ql;
      float bv, scale = 1.0f;
      if (EPI == 0) {
        const int seg = gcol / 768;
        const int cw = gcol - seg*768;
        bv = (seg == 0) ? b0[cw] : ((seg == 1) ? b1[cw] : b2[cw]);
        if (seg == 0) scale = scaleQ;
      } else if (EPI == 1) {
        bv = (zz == 0) ? b0[gcol] : 0.0f;
      } else {
        bv = b0[gcol];
      }
      f32x4 v = acc[fm][fn];
      #pragma unroll
      for (int j = 0; j < 4; ++j) {
        float val = (v[j] + bv) * scale;
        if (EPI == 0) {
          outB[(size_t)(rowb + j) * 2304 + gcol] = f2b(val);
        } else if (EPI == 1) {
          outF[(size_t)zz * (Mm*768) + (size_t)(rowb + j) * 768 + gcol] = val;
        } else {
          float arg = 0.7978845608028654f * (val + 0.044715f * val * val * val);
          float e = __expf(2.0f * arg);
          float g = 0.5f * val * (2.0f - 2.0f / (e + 1.0f));
          outB[(size_t)(rowb + j) * 3072 + gcol] = f2b(g);
        }
      }
    }
  }
}

template<int EPI>
__global__ __launch_bounds__(256) void gemm3_kernel(
    const u16* __restrict__ A, const u16* __restrict__ Bw,
    const float* __restrict__ b0, const float* __restrict__ b1, const float* __restrict__ b2,
    int Kfull, int Kc, float scaleQ,
    float* __restrict__ outF, u16* __restrict__ outB)
{
  __shared__ __align__(16) char smem[49152];
  gemm_body<EPI>(smem, blockIdx.x, blockIdx.y, gridDim.x, gridDim.x*gridDim.y,
                 blockIdx.z, A, Bw, b0, b1, b2, Kfull, Kc, scaleQ, outF, outB);
}

// ---------------- FUSED: FFN2 GEMM (blocks 0..575, grid (12,12,4) flattened) +
// wconv of NEXT layer's weights into the other slot (blocks 576..2303).
__global__ __launch_bounds__(256) void ffn2w_kernel(
    const u16* __restrict__ A, const u16* __restrict__ w2T,
    const float* __restrict__ b2v, float* __restrict__ outF,
    const float* __restrict__ Wq, const float* __restrict__ Wk, const float* __restrict__ Wv,
    const float* __restrict__ Wo, const float* __restrict__ W1, const float* __restrict__ W2,
    int layerNext, u16* __restrict__ slotNext, int doW)
{
  __shared__ __align__(16) char smem[49152];
  const int bid = blockIdx.x;
  if (bid < 576) {
    const int zz = bid / 144, r = bid - zz*144;
    gemm_body<1>(smem, r % 12, r / 12, 12, 144, zz,
                 A, w2T, b2v, b2v, b2v, 3072, 768, 1.0f, outF, nullptr);
  } else if (doW) {
    wconv_body(bid - 576, layerNext, smem, Wq, Wk, Wv, Wo, W1, W2, slotNext);
  }
}

// ---------------- MFMA attention: block = (b, h, pair of 64-q-row tiles)
template<int PREBIAS>
__global__ __launch_bounds__(256) void attn2_kernel(
    const u16* __restrict__ qkv,         // [1536][2304] bf16 q|k|v (q pre-scaled)
    const u16* __restrict__ biasb,       // tt-paired chunk layout (PREBIAS=1)
    const float* __restrict__ atb, const int* __restrict__ sp, const int* __restrict__ spT,
    const float* __restrict__ sp_emb, const float* __restrict__ sp_emb_rev,
    u16* __restrict__ ab)                // [1536][768] bf16
{
  __shared__ __align__(16) u16 Kt[384][32];   // [m][d(24)+pad]
  __shared__ __align__(16) u16 Vt[32][392];   // [d(24)+pad][m] transposed
  __shared__ __align__(16) u16 Qt[128][32];   // both q-tiles
  __shared__ __align__(16) u16 Pw[4][16][32]; // per-wave P chunk
  __shared__ float spc[512], sprc[512];
  const int bid = blockIdx.x;
  const int pair = bid % 3;
  const int h = (bid / 3) % Hh;
  const int b = bid / (3 * Hh);
  const int t = threadIdx.x, lane = t & 63, wave = t >> 6;
  const int ql = lane & 15, hi = lane >> 4;

  for (int idx = t; idx < 384*3; idx += 256) {         // K + V^T staging, 16B loads
    const int m = idx / 3, c = idx - m*3;
    const u16* base = qkv + ((size_t)m*Bb + b)*2304 + h*24 + c*8;
    uint4 kk = *(const uint4*)(base + 768);
    uint4 vv = *(const uint4*)(base + 1536);
    *(uint4*)&Kt[m][c*8] = kk;
    Vt[c*8+0][m] = (u16)(vv.x & 0xffffu); Vt[c*8+1][m] = (u16)(vv.x >> 16);
    Vt[c*8+2][m] = (u16)(vv.y & 0xffffu); Vt[c*8+3][m] = (u16)(vv.y >> 16);
    Vt[c*8+4][m] = (u16)(vv.z & 0xffffu); Vt[c*8+5][m] = (u16)(vv.z >> 16);
    Vt[c*8+6][m] = (u16)(vv.w & 0xffffu); Vt[c*8+7][m] = (u16)(vv.w >> 16);
  }
  for (int idx = t; idx < 384*2; idx += 256)           // K d-pad
    *(uint2*)&Kt[idx>>1][24 + (idx&1)*4] = make_uint2(0u, 0u);
  for (int idx = t; idx < 8*196; idx += 256)           // V^T d-pad rows
    *(unsigned*)((char*)&Vt[24][0] + idx*4) = 0u;
  for (int idx = t; idx < 128*3; idx += 256) {         // Q: both tiles upfront, 16B loads
    const int qr = idx / 3, c = idx - qr*3;
    const u16* base = qkv + ((size_t)(pair*128 + qr)*Bb + b)*2304 + h*24 + c*8;
    *(uint4*)&Qt[qr][c*8] = *(const uint4*)base;
  }
  for (int idx = t; idx < 128*2; idx += 256)           // Q d-pad
    *(uint2*)&Qt[idx>>1][24 + (idx&1)*4] = make_uint2(0u, 0u);
  if (!PREBIAS) {
    for (int i = t; i < 512; i += 256) {
      spc[i]  = sp_emb[(size_t)i*Hh + h];
      sprc[i] = sp_emb_rev[(size_t)i*Hh + h];
    }
  }
  __syncthreads();   // all staging done; loop below is barrier-free

  for (int qi = 0; qi < 2; ++qi) {
    const int ntile = pair*2 + qi;
    const int q0 = ntile*64 + wave*16;
    const int q = q0 + ql;
    const bf16x8 qf = *(const bf16x8*)&Qt[qi*64 + wave*16 + ql][hi*8];

    f32x4 f[24];
    const size_t crow = ((size_t)b*Nn + q)*Nn;
    if (PREBIAS) {
      const u16* bp = biasb + (((size_t)(b*Hh + h)*24 + ntile*4 + wave)*24)*256 + lane*8;
      #pragma unroll
      for (int tt2 = 0; tt2 < 12; ++tt2) {
        uint4 bb = *(const uint4*)(bp + tt2*512);
        {
          bf16x8 kf = *(const bf16x8*)&Kt[(2*tt2)*16 + ql][hi*8];
          f32x4 z = (f32x4){0.f,0.f,0.f,0.f};
          f32x4 s = __builtin_amdgcn_mfma_f32_16x16x32_bf16(kf, qf, z, 0, 0, 0);
          s[0] += b2f((u16)(bb.x & 0xffffu)); s[1] += b2f((u16)(bb.x >> 16));
          s[2] += b2f((u16)(bb.y & 0xffffu)); s[3] += b2f((u16)(bb.y >> 16));
          f[2*tt2] = s;
        }
        {
          bf16x8 kf = *(const bf16x8*)&Kt[(2*tt2+1)*16 + ql][hi*8];
          f32x4 z = (f32x4){0.f,0.f,0.f,0.f};
          f32x4 s = __builtin_amdgcn_mfma_f32_16x16x32_bf16(kf, qf, z, 0, 0, 0);
          s[0] += b2f((u16)(bb.z & 0xffffu)); s[1] += b2f((u16)(bb.z >> 16));
          s[2] += b2f((u16)(bb.w & 0xffffu)); s[3] += b2f((u16)(bb.w >> 16));
          f[2*tt2+1] = s;
        }
      }
    } else {
      #pragma unroll
      for (int tt = 0; tt < 24; ++tt) {
        bf16x8 kf = *(const bf16x8*)&Kt[tt*16 + ql][hi*8];
        f32x4 z = (f32x4){0.f,0.f,0.f,0.f};
        f32x4 s = __builtin_amdgcn_mfma_f32_16x16x32_bf16(kf, qf, z, 0, 0, 0);
        const int off = tt*16 + hi*4;
        int4 s4 = *(const int4*)(sp + crow + off);
        int4 t4 = *(const int4*)(spT + crow + off);
        float4 a4 = *(const float4*)(atb + crow + off);
        s[0] += a4.x + spc[s4.x] + sprc[t4.x];
        s[1] += a4.y + spc[s4.y] + sprc[t4.y];
        s[2] += a4.z + spc[s4.z] + sprc[t4.z];
        s[3] += a4.w + spc[s4.w] + sprc[t4.w];
        f[tt] = s;
      }
    }

    float mx = -3.0e38f;
    #pragma unroll
    for (int tt = 0; tt < 24; ++tt)
      mx = fmaxf(mx, fmaxf(fmaxf(f[tt][0], f[tt][1]), fmaxf(f[tt][2], f[tt][3])));
    mx = fmaxf(mx, __shfl_xor(mx, 16, 64));
    mx = fmaxf(mx, __shfl_xor(mx, 32, 64));
    float sum = 0.f;
    #pragma unroll
    for (int tt = 0; tt < 24; ++tt) {
      #pragma unroll
      for (int j = 0; j < 4; ++j) { f[tt][j] = __expf(f[tt][j] - mx); sum += f[tt][j]; }
    }
    sum += __shfl_xor(sum, 16, 64);
    sum += __shfl_xor(sum, 32, 64);
    const float inv = 1.0f / sum;

    f32x4 o0 = (f32x4){0.f,0.f,0.f,0.f}, o1 = (f32x4){0.f,0.f,0.f,0.f};
    char* prow = (char*)&Pw[wave][ql][0];
    const int swz = (ql & 3) << 4;
    #pragma unroll
    for (int c = 0; c < 12; ++c) {
      unsigned w0 = pkcvt(f[2*c][0],   f[2*c][1]);
      unsigned w1 = pkcvt(f[2*c][2],   f[2*c][3]);
      unsigned w2 = pkcvt(f[2*c+1][0], f[2*c+1][1]);
      unsigned w3 = pkcvt(f[2*c+1][2], f[2*c+1][3]);
      *(unsigned*)(prow + (((hi*8)      ) ^ swz)) = w0;
      *(unsigned*)(prow + (((hi*8) +  4) ^ swz)) = w1;
      *(unsigned*)(prow + (((hi*8) + 32) ^ swz)) = w2;
      *(unsigned*)(prow + (((hi*8) + 36) ^ swz)) = w3;
      bf16x8 a = *(const bf16x8*)(prow + ((hi*16) ^ swz));
      bf16x8 v0 = *(const bf16x8*)&Vt[ql][c*32 + hi*8];
      bf16x8 v1 = *(const bf16x8*)&Vt[16 + ql][c*32 + hi*8];
      o0 = __builtin_amdgcn_mfma_f32_16x16x32_bf16(a, v0, o0, 0, 0, 0);
      o1 = __builtin_amdgcn_mfma_f32_16x16x32_bf16(a, v1, o1, 0, 0, 0);
    }

    #pragma unroll
    for (int j = 0; j < 4; ++j) {
      float invj = __shfl(inv, hi*4 + j, 64);
      const int qg = q0 + hi*4 + j;
      u16* orow = ab + ((size_t)qg*Bb + b)*Ee + h*24;
      orow[ql] = f2b(o0[j] * invj);
      if (ql < 8) orow[16 + ql] = f2b(o1[j] * invj);
    }
  }
}

// ---------------- residual + LayerNorm: wave-per-row, no block barriers, float4 loads
template<int NP>
__global__ __launch_bounds__(256) void ln_kernel(
    const float* __restrict__ xin, const float* __restrict__ delta,
    const float* __restrict__ gamma, const float* __restrict__ beta,
    float* __restrict__ xout, u16* __restrict__ xb)
{
  const int wave = threadIdx.x >> 6, lane = threadIdx.x & 63;
  const int r = blockIdx.x * 4 + wave;
  const size_t base = (size_t)r * Ee;
  const int c0 = lane * 12;
  float v[12];
  #pragma unroll
  for (int i = 0; i < 3; ++i) {
    float4 xv = *(const float4*)(xin + base + c0 + i*4);
    v[i*4+0] = xv.x; v[i*4+1] = xv.y; v[i*4+2] = xv.z; v[i*4+3] = xv.w;
  }
  #pragma unroll
  for (int p = 0; p < NP; ++p) {
    const float* dp = delta + (size_t)p*(Mm*768) + base + c0;
    #pragma unroll
    for (int i = 0; i < 3; ++i) {
      float4 dv = *(const float4*)(dp + i*4);
      v[i*4+0] += dv.x; v[i*4+1] += dv.y; v[i*4+2] += dv.z; v[i*4+3] += dv.w;
    }
  }
  float s = 0.f;
  #pragma unroll
  for (int i = 0; i < 12; ++i) s += v[i];
  #pragma unroll
  for (int off = 1; off < 64; off <<= 1) s += __shfl_xor(s, off, 64);
  const float mean = s * (1.0f / 768.0f);
  float qs = 0.f;
  #pragma unroll
  for (int i = 0; i < 12; ++i) { float d = v[i] - mean; qs += d * d; }
  #pragma unroll
  for (int off = 1; off < 64; off <<= 1) qs += __shfl_xor(qs, off, 64);
  const float rstd = rsqrtf(qs * (1.0f / 768.0f) + 1e-5f);
  float o[12];
  #pragma unroll
  for (int i = 0; i < 3; ++i) {
    float4 g4 = *(const float4*)(gamma + c0 + i*4);
    float4 b4 = *(const float4*)(beta + c0 + i*4);
    o[i*4+0] = (v[i*4+0] - mean) * rstd * g4.x + b4.x;
    o[i*4+1] = (v[i*4+1] - mean) * rstd * g4.y + b4.y;
    o[i*4+2] = (v[i*4+2] - mean) * rstd * g4.z + b4.z;
    o[i*4+3] = (v[i*4+3] - mean) * rstd * g4.w + b4.w;
    *(float4*)(xout + base + c0 + i*4) = make_float4(o[i*4+0], o[i*4+1], o[i*4+2], o[i*4+3]);
  }
  #pragma unroll
  for (int i = 0; i < 3; ++i) {
    uint2 u;
    u.x = pkcvt(o[i*4+0], o[i*4+1]);
    u.y = pkcvt(o[i*4+2], o[i*4+3]);
    *(uint2*)(xb + base + c0 + i*4) = u;
  }
}

extern "C" void kernel_launch(void* const* d_in, const int* in_sizes, int n_in,
                              void* d_out, int out_size, void* d_ws, size_t ws_size,
                              hipStream_t stream) {
  const int*   node_type  = (const int*)d_in[0];
  const float* nif        = (const float*)d_in[1];
  const int*   in_deg     = (const int*)d_in[2];
  const int*   out_deg    = (const int*)d_in[3];
  const float* atb        = (const float*)d_in[4];
  const int*   sp         = (const int*)d_in[5];
  const float* node_emb   = (const float*)d_in[6];
  const float* ind_emb    = (const float*)d_in[7];
  const float* outd_emb   = (const float*)d_in[8];
  const float* sp_emb     = (const float*)d_in[9];
  const float* sp_emb_rev = (const float*)d_in[10];
  const float* Wq = (const float*)d_in[11]; const float* bq = (const float*)d_in[12];
  const float* Wk = (const float*)d_in[13]; const float* bk = (const float*)d_in[14];
  const float* Wv = (const float*)d_in[15]; const float* bv = (const float*)d_in[16];
  const float* Wo = (const float*)d_in[17]; const float* bo = (const float*)d_in[18];
  const float* W1 = (const float*)d_in[19]; const float* b1 = (const float*)d_in[20];
  const float* W2 = (const float*)d_in[21]; const float* b2 = (const float*)d_in[22];
  const float* ln1s = (const float*)d_in[23]; const float* ln1b = (const float*)d_in[24];
  const float* ln2s = (const float*)d_in[25]; const float* ln2b = (const float*)d_in[26];

  char* ws = (char*)d_ws;
  float* x      = (float*)(ws);                    //  4,718,592
  u16*   xb     = (u16*)(ws +  4718592);           //  2,359,296
  u16*   qkvb16 = (u16*)(ws +  7077888);           //  7,077,888
  u16*   abuf   = (u16*)(ws + 14155776);           //  2,359,296
  u16*   hb     = (u16*)(ws + 16515072);           //  9,437,184
  float* obufP  = (float*)(ws + 25952256);         // 18,874,368 (4 partials)
  int*   spTb   = (int*)(ws + 44826624);           //  2,359,296
  u16*   biasb  = (u16*)(ws + 47185920);           // 37,748,736 -> 84,934,656
  u16*   wTs0   = (u16*)(ws + 84934656);           // 14,155,776
  u16*   wTs1   = (u16*)(ws + 99090432);           // 14,155,776 -> 113,246,208
  const bool useBias = ws_size >= 113246208ull;
  u16* slots[2] = { wTs0, wTs1 };

  // fused upfront: embed | spT | wconv(l0)  (all independent)
  prep_kernel<<<3840, 256, 0, stream>>>(node_type, nif, in_deg, out_deg,
                                        node_emb, ind_emb, outd_emb, x, xb,
                                        sp, spTb,
                                        Wq, Wk, Wv, Wo, W1, W2, slots[0]);
  if (useBias)
    bias_pre_kernel<<<dim3(24, 32, 4), 256, 0, stream>>>(atb, sp, spTb,
                                                         sp_emb, sp_emb_rev, biasb);

  const float scaleQ = 0.2041241452319315f;  // 24^-0.5

  for (int l = 0; l < Ll; ++l) {
    const float *bql = bq + (size_t)l*Ee, *bkl = bk + (size_t)l*Ee, *bvl = bv + (size_t)l*Ee;
    const float *bol = bo + (size_t)l*Ee;
    const float *b1l = b1 + (size_t)l*Ff, *b2l = b2 + (size_t)l*Ee;

    u16* slot = slots[l & 1];
    u16* slotN = slots[(l + 1) & 1];
    const u16* qkvT = slot;
    const u16* woT  = slot + 1769472;
    const u16* w1T  = slot + 2359296;
    const u16* w2T  = slot + 4718592;

    // QKV: [1536,768] @ [2304,768]^T -> bf16 [1536][2304]
    gemm3_kernel<0><<<dim3(12, 36), 256, 0, stream>>>(xb, qkvT, bql, bkl, bvl,
                                                      768, 768, scaleQ, nullptr, qkvb16);
    if (useBias)
      attn2_kernel<1><<<384, 256, 0, stream>>>(qkvb16, biasb, atb, sp, spTb,
                                               sp_emb, sp_emb_rev, abuf);
    else
      attn2_kernel<0><<<384, 256, 0, stream>>>(qkvb16, nullptr, atb, sp, spTb,
                                               sp_emb, sp_emb_rev, abuf);
    // O-proj: split-K 2 -> partials
    gemm3_kernel<1><<<dim3(12, 12, 2), 256, 0, stream>>>(abuf, woT, bol, bol, bol,
                                                         768, 384, 1.0f, obufP, nullptr);
    ln_kernel<2><<<Mm/4, 256, 0, stream>>>(x, obufP, ln1s + (size_t)l*Ee, ln1b + (size_t)l*Ee, x, xb);
    // FFN1 + gelu -> bf16 hidden
    gemm3_kernel<2><<<dim3(12, 48), 256, 0, stream>>>(xb, w1T, b1l, b1l, b1l,
                                                      768, 768, 1.0f, nullptr, hb);
    // FFN2 split-K 4 (blocks 0..575)  FUSED with  wconv(layer l+1) -> other slot
    ffn2w_kernel<<<2304, 256, 0, stream>>>(hb, w2T, b2l, obufP,
                                           Wq, Wk, Wv, Wo, W1, W2,
                                           l + 1, slotN, (l + 1 < Ll) ? 1 : 0);
    float* xdst = (l == Ll - 1) ? (float*)d_out : x;
    ln_kernel<4><<<Mm/4, 256, 0, stream>>>(x, obufP, ln2s + (size_t)l*Ee, ln2b + (size_t)l*Ee, xdst, xb);
  }
}

// Round 21
// 1173.413 us; speedup vs baseline: 1.0188x; 1.0072x over previous
//
#include <hip/hip_runtime.h>
#include <hip/hip_bf16.h>

#define Bb 4
#define Nn 384
#define Ee 768
#define Hh 32
#define Ff 3072
#define Ll 12
#define Ss 512
#define Mm (Nn*Bb)   // 1536 tokens

typedef __attribute__((ext_vector_type(8))) short bf16x8;
typedef __attribute__((ext_vector_type(4))) float f32x4;
typedef unsigned short u16;

__device__ __forceinline__ u16 f2b(float f) {
  union { float f; unsigned int i; } c; c.f = f;
  unsigned int x = c.i;
  return (u16)((x + 0x7fffu + ((x >> 16) & 1u)) >> 16); // RNE
}
__device__ __forceinline__ float b2f(u16 u) {
  union { unsigned int i; float f; } c; c.i = ((unsigned int)u) << 16; return c.f;
}
__device__ __forceinline__ unsigned pkcvt(float lo, float hi) {
  unsigned r;
  asm("v_cvt_pk_bf16_f32 %0, %1, %2" : "=v"(r) : "v"(lo), "v"(hi));
  return r;
}
__device__ __forceinline__ void gload_lds16(const void* g, void* l) {
  __builtin_amdgcn_global_load_lds((__attribute__((address_space(1))) void*)(g),
                                   (__attribute__((address_space(3))) void*)(l), 16, 0, 0);
}

// ---------------- embed body
__device__ __forceinline__ void embed_body(
    int r, const int* __restrict__ node_type, const float* __restrict__ nif,
    const int* __restrict__ in_deg, const int* __restrict__ out_deg,
    const float* __restrict__ node_emb, const float* __restrict__ ind_emb,
    const float* __restrict__ outd_emb,
    float* __restrict__ x, u16* __restrict__ xb)
{
  const int n = r / Bb, b = r % Bb;
  const int nt  = node_type[b*Nn + n];
  const int idg = in_deg[b*Nn + n];
  const int odg = out_deg[b*Nn + n];
  for (int c = threadIdx.x; c < Ee; c += 256) {
    float val = node_emb[(size_t)nt*Ee + c] + ind_emb[(size_t)idg*Ee + c]
              + outd_emb[(size_t)odg*Ee + c] + nif[((size_t)b*Nn + n)*Ee + c];
    x[(size_t)r*Ee + c] = val;
    xb[(size_t)r*Ee + c] = f2b(val);
  }
}

// ---------------- spT body (32x33 LDS tile transpose, 256 1-D threads): bid in [0,576)
__device__ __forceinline__ void spT_body(
    int bid, char* smemRaw, const int* __restrict__ sp, int* __restrict__ spT)
{
  int (*tile)[33] = (int(*)[33])smemRaw;
  const int b = bid / 144, rem = bid % 144;
  const int m0 = (rem % 12) * 32, n0 = (rem / 12) * 32;
  const int tx = threadIdx.x & 31, ty = threadIdx.x >> 5;
  for (int i = ty; i < 32; i += 8)
    tile[i][tx] = sp[((size_t)b*Nn + n0 + i)*Nn + m0 + tx];
  __syncthreads();
  for (int i = ty; i < 32; i += 8)
    spT[((size_t)b*Nn + m0 + i)*Nn + n0 + tx] = tile[tx][i];
}

// ---------------- bias_pre body (coalesced, spT-based), tt-PAIRED chunk layout: bid2 in [0,3072)
__device__ __forceinline__ void biaspre_body(
    int bid2, char* smemRaw,
    const float* __restrict__ atb, const int* __restrict__ sp, const int* __restrict__ spT,
    const float* __restrict__ sp_emb, const float* __restrict__ sp_emb_rev,
    u16* __restrict__ biasb)
{
  float* spc  = (float*)smemRaw;
  float* sprc = spc + 512;
  const int bx = bid2 % 24, h = (bid2 / 24) % Hh, b = bid2 / (24 * Hh);
  const int t = threadIdx.x;
  for (int i = t; i < 512; i += 256) {
    spc[i]  = sp_emb[(size_t)i*Hh + h];
    sprc[i] = sp_emb_rev[(size_t)i*Hh + h];
  }
  __syncthreads();
  const int qi = t >> 4;                 // 0..15 (q lane)
  const int ml = (t & 15) << 2;          // m within 64-group, multiple of 4
  const size_t rowb = ((size_t)b*Nn + bx*16 + qi)*Nn;
  u16* outb = biasb + ((size_t)(b*Hh + h)*24 + bx)*24*256;
  #pragma unroll
  for (int mg = 0; mg < 6; ++mg) {
    const int m = mg*64 + ml;
    float4 a4 = *(const float4*)(atb + rowb + m);
    int4  s4 = *(const int4*)(sp  + rowb + m);
    int4  t4 = *(const int4*)(spT + rowb + m);
    const int tt = m >> 4, hi2 = (m >> 2) & 3;
    uint2 u;
    u.x = pkcvt(a4.x + spc[s4.x] + sprc[t4.x], a4.y + spc[s4.y] + sprc[t4.y]);
    u.y = pkcvt(a4.z + spc[s4.z] + sprc[t4.z], a4.w + spc[s4.w] + sprc[t4.w]);
    *(uint2*)(outb + (tt >> 1)*512 + (hi2*16 + qi)*8 + (tt & 1)*4) = u;
  }
}

// ---------------- wconv body (shared): tid in [0,1728)
__device__ __forceinline__ void wconv_body(
    int tid, int layer, char* smemRaw,
    const float* Wq, const float* Wk, const float* Wv,
    const float* Wo, const float* W1, const float* W2, u16* slot)
{
  float (*tile)[65] = (float(*)[65])smemRaw;
  const float* src; u16* dst; int Ns, Ks;
  if (tid < 432)       { int seg = tid / 144; tid -= seg*144;
                         src = (seg==0?Wq:(seg==1?Wk:Wv)) + (size_t)layer*Ee*Ee;
                         dst = slot + (size_t)seg*589824; Ns = 768; Ks = 768; }
  else if (tid < 576)  { tid -= 432; src = Wo + (size_t)layer*Ee*Ee; dst = slot + 1769472; Ns = 768;  Ks = 768; }
  else if (tid < 1152) { tid -= 576; src = W1 + (size_t)layer*Ee*Ff; dst = slot + 2359296; Ns = 3072; Ks = 768; }
  else                 { tid -= 1152; src = W2 + (size_t)layer*Ff*Ee; dst = slot + 4718592; Ns = 768; Ks = 3072; }
  const int tc = Ns >> 6;
  const int tk = tid / tc, tn = tid % tc;
  const int t = threadIdx.x;
  #pragma unroll
  for (int i = 0; i < 4; ++i) {
    const int id = t + i*256;
    const int r = id >> 4, c = (id & 15) << 2;
    float4 v = *(const float4*)(src + (size_t)(tk*64 + r)*Ns + tn*64 + c);
    tile[r][c+0] = v.x; tile[r][c+1] = v.y; tile[r][c+2] = v.z; tile[r][c+3] = v.w;
  }
  __syncthreads();
  #pragma unroll
  for (int i = 0; i < 2; ++i) {
    const int ch = t + i*256;
    const int n = ch >> 3, kc = (ch & 7) << 3;
    uint4 u;
    u.x = pkcvt(tile[kc+0][n], tile[kc+1][n]);
    u.y = pkcvt(tile[kc+2][n], tile[kc+3][n]);
    u.z = pkcvt(tile[kc+4][n], tile[kc+5][n]);
    u.w = pkcvt(tile[kc+6][n], tile[kc+7][n]);
    *(uint4*)(dst + (size_t)(tn*64 + n)*Ks + tk*64 + kc) = u;
  }
}

__global__ __launch_bounds__(256) void wconv_kernel(
    const float* __restrict__ Wq, const float* __restrict__ Wk, const float* __restrict__ Wv,
    const float* __restrict__ Wo, const float* __restrict__ W1, const float* __restrict__ W2,
    int layer, u16* __restrict__ slot)
{
  __shared__ __align__(16) char smem[16640];
  wconv_body(blockIdx.x, layer, smem, Wq, Wk, Wv, Wo, W1, W2, slot);
}

// ---------------- FUSED upfront: embed (0..1535) | spT (1536..2111) | wconv l0 (2112..3839)
__global__ __launch_bounds__(256) void prep_kernel(
    const int* __restrict__ node_type, const float* __restrict__ nif,
    const int* __restrict__ in_deg, const int* __restrict__ out_deg,
    const float* __restrict__ node_emb, const float* __restrict__ ind_emb,
    const float* __restrict__ outd_emb,
    float* __restrict__ x, u16* __restrict__ xb,
    const int* __restrict__ sp, int* __restrict__ spT,
    const float* __restrict__ Wq, const float* __restrict__ Wk, const float* __restrict__ Wv,
    const float* __restrict__ Wo, const float* __restrict__ W1, const float* __restrict__ W2,
    u16* __restrict__ slot0)
{
  __shared__ __align__(16) char smem[16640];
  const int bid = blockIdx.x;
  if (bid < 1536) {
    embed_body(bid, node_type, nif, in_deg, out_deg, node_emb, ind_emb, outd_emb, x, xb);
  } else if (bid < 2112) {
    spT_body(bid - 1536, smem, sp, spT);
  } else {
    wconv_body(bid - 2112, 0, smem, Wq, Wk, Wv, Wo, W1, W2, slot0);
  }
}

// ---------------- 128x64-tile GEMM, BK=64, counted-vmcnt 2-barrier pipeline, XCD-swizzled
// EPI 0: qkv fused bias (Q scaled) -> bf16 out ld 2304
// EPI 1: f32 partial out ld 768 (bias only on z==0)
// EPI 2: gelu -> bf16 out ld 3072
template<int EPI>
__device__ __forceinline__ void gemm_body(
    char* smemRaw, int bx0, int by0, int gx, int nwg, int zz,
    const u16* __restrict__ A, const u16* __restrict__ Bw,
    const float* __restrict__ b0, const float* __restrict__ b1, const float* __restrict__ b2,
    int Kfull, int Kc, float scaleQ,
    float* __restrict__ outF, u16* __restrict__ outB)
{
  u16 (*As)[128][64] = (u16(*)[128][64])smemRaw;            // 2 x 16KB
  u16 (*Bs)[64][64]  = (u16(*)[64][64])(smemRaw + 32768);   // 2 x 8KB
  const int t = threadIdx.x, lane = t & 63, wave = t >> 6;
  int bx = bx0, by = by0;
  { // XCD swizzle (nwg always divisible by 8)
    const int bid = bx + gx * by;
    const int cpx = nwg >> 3;
    const int s = (bid & 7) * cpx + (bid >> 3);
    bx = s % gx; by = s / gx;
  }
  const int m0 = bx * 128, n0 = by * 64;
  const int k0 = zz * Kc;
  const int wm = wave >> 1, wn = wave & 1;
  const int ql = lane & 15, hi = lane >> 4;
  const int nk = Kc >> 6;
  const int sr = t >> 3;
  const int sslot = (t & 7) ^ (sr & 7);
  const size_t aoff = (size_t)(m0 + sr)*Kfull + k0 + (sslot << 3);
  const size_t boff = (size_t)(n0 + sr)*Kfull + k0 + (sslot << 3);
  const size_t rstep = (size_t)32 * Kfull;

  int aro[4][2], bro[2][2];
  #pragma unroll
  for (int ks = 0; ks < 2; ++ks) {
    const int kb = (((ks<<2) + hi) ^ (ql & 7)) << 4;
    #pragma unroll
    for (int f = 0; f < 4; ++f) aro[f][ks] = (wm*64 + f*16 + ql)*128 + kb;
    #pragma unroll
    for (int f = 0; f < 2; ++f) bro[f][ks] = (wn*32 + f*16 + ql)*128 + kb;
  }

  f32x4 acc[4][2];
  #pragma unroll
  for (int a = 0; a < 4; ++a)
    #pragma unroll
    for (int c = 0; c < 2; ++c) acc[a][c] = (f32x4){0.f,0.f,0.f,0.f};

  #pragma unroll
  for (int i = 0; i < 4; ++i)
    gload_lds16(A + aoff + i*rstep, (char*)&As[0][0][0] + i*4096 + t*16);
  #pragma unroll
  for (int i = 0; i < 2; ++i)
    gload_lds16(Bw + boff + i*rstep, (char*)&Bs[0][0][0] + i*4096 + t*16);

  for (int kt = 0; kt < nk; ++kt) {
    const int cur = kt & 1, nxt = cur ^ 1;
    const bool pre = (kt + 1 < nk);
    if (pre) {
      const size_t kk = (size_t)(kt + 1) << 6;
      #pragma unroll
      for (int i = 0; i < 4; ++i)
        gload_lds16(A + aoff + kk + i*rstep, (char*)&As[nxt][0][0] + i*4096 + t*16);
      #pragma unroll
      for (int i = 0; i < 2; ++i)
        gload_lds16(Bw + boff + kk + i*rstep, (char*)&Bs[nxt][0][0] + i*4096 + t*16);
      asm volatile("s_waitcnt vmcnt(6)" ::: "memory");   // tile kt landed; kt+1 in flight
    } else {
      asm volatile("s_waitcnt vmcnt(0)" ::: "memory");
    }
    __builtin_amdgcn_s_barrier();            // B1
    __builtin_amdgcn_sched_barrier(0);

    const char* aBase = (const char*)&As[cur][0][0];
    const char* bBase = (const char*)&Bs[cur][0][0];
    bf16x8 af[4][2], bf[2][2];
    #pragma unroll
    for (int f = 0; f < 4; ++f)
      #pragma unroll
      for (int ks = 0; ks < 2; ++ks)
        af[f][ks] = *(const bf16x8*)(aBase + aro[f][ks]);
    #pragma unroll
    for (int f = 0; f < 2; ++f)
      #pragma unroll
      for (int ks = 0; ks < 2; ++ks)
        bf[f][ks] = *(const bf16x8*)(bBase + bro[f][ks]);
    #pragma unroll
    for (int ks = 0; ks < 2; ++ks)
      #pragma unroll
      for (int fm = 0; fm < 4; ++fm)
        #pragma unroll
        for (int fn = 0; fn < 2; ++fn)
          acc[fm][fn] = __builtin_amdgcn_mfma_f32_16x16x32_bf16(af[fm][ks], bf[fn][ks], acc[fm][fn], 0, 0, 0);
    if (pre) {
      __builtin_amdgcn_sched_barrier(0);
      __builtin_amdgcn_s_barrier();          // B2: cur reads drained before overwrite
    }
  }

  #pragma unroll
  for (int fm = 0; fm < 4; ++fm) {
    const int rowb = m0 + wm*64 + fm*16 + hi*4;
    #pragma unroll
    for (int fn = 0; fn < 2; ++fn) {
      const int gcol = n0 + wn*32 + fn*16 + ql;
      float bv, scale = 1.0f;
      if (EPI == 0) {
        const int seg = gcol / 768;
        const int cw = gcol - seg*768;
        bv = (seg == 0) ? b0[cw] : ((seg == 1) ? b1[cw] : b2[cw]);
        if (seg == 0) scale = scaleQ;
      } else if (EPI == 1) {
        bv = (zz == 0) ? b0[gcol] : 0.0f;
      } else {
        bv = b0[gcol];
      }
      f32x4 v = acc[fm][fn];
      #pragma unroll
      for (int j = 0; j < 4; ++j) {
        float val = (v[j] + bv) * scale;
        if (EPI == 0) {
          outB[(size_t)(rowb + j) * 2304 + gcol] = f2b(val);
        } else if (EPI == 1) {
          outF[(size_t)zz * (Mm*768) + (size_t)(rowb + j) * 768 + gcol] = val;
        } else {
          float arg = 0.7978845608028654f * (val + 0.044715f * val * val * val);
          float e = __expf(2.0f * arg);
          float g = 0.5f * val * (2.0f - 2.0f / (e + 1.0f));
          outB[(size_t)(rowb + j) * 3072 + gcol] = f2b(g);
        }
      }
    }
  }
}

template<int EPI>
__global__ __launch_bounds__(256) void gemm3_kernel(
    const u16* __restrict__ A, const u16* __restrict__ Bw,
    const float* __restrict__ b0, const float* __restrict__ b1, const float* __restrict__ b2,
    int Kfull, int Kc, float scaleQ,
    float* __restrict__ outF, u16* __restrict__ outB)
{
  __shared__ __align__(16) char smem[49152];
  gemm_body<EPI>(smem, blockIdx.x, blockIdx.y, gridDim.x, gridDim.x*gridDim.y,
                 blockIdx.z, A, Bw, b0, b1, b2, Kfull, Kc, scaleQ, outF, outB);
}

// ---------------- FUSED: QKV l0 GEMM (blocks 0..431, grid (12,36) flattened) +
// bias_pre (blocks 432..3503) — both depend only on prep outputs; attn(l0) consumes both.
__global__ __launch_bounds__(256) void qkv0b_kernel(
    const u16* __restrict__ A, const u16* __restrict__ qkvT,
    const float* __restrict__ b0, const float* __restrict__ b1, const float* __restrict__ b2,
    float scaleQ, u16* __restrict__ outB,
    const float* __restrict__ atb, const int* __restrict__ sp, const int* __restrict__ spT,
    const float* __restrict__ sp_emb, const float* __restrict__ sp_emb_rev,
    u16* __restrict__ biasb)
{
  __shared__ __align__(16) char smem[49152];
  const int bid = blockIdx.x;
  if (bid < 432) {
    gemm_body<0>(smem, bid % 12, bid / 12, 12, 432, 0,
                 A, qkvT, b0, b1, b2, 768, 768, scaleQ, nullptr, outB);
  } else {
    biaspre_body(bid - 432, smem, atb, sp, spT, sp_emb, sp_emb_rev, biasb);
  }
}

// ---------------- FUSED: FFN2 GEMM (blocks 0..575, grid (12,12,4) flattened) +
// wconv of NEXT layer's weights into the other slot (blocks 576..2303).
__global__ __launch_bounds__(256) void ffn2w_kernel(
    const u16* __restrict__ A, const u16* __restrict__ w2T,
    const float* __restrict__ b2v, float* __restrict__ outF,
    const float* __restrict__ Wq, const float* __restrict__ Wk, const float* __restrict__ Wv,
    const float* __restrict__ Wo, const float* __restrict__ W1, const float* __restrict__ W2,
    int layerNext, u16* __restrict__ slotNext, int doW)
{
  __shared__ __align__(16) char smem[49152];
  const int bid = blockIdx.x;
  if (bid < 576) {
    const int zz = bid / 144, r = bid - zz*144;
    gemm_body<1>(smem, r % 12, r / 12, 12, 144, zz,
                 A, w2T, b2v, b2v, b2v, 3072, 768, 1.0f, outF, nullptr);
  } else if (doW) {
    wconv_body(bid - 576, layerNext, smem, Wq, Wk, Wv, Wo, W1, W2, slotNext);
  }
}

// ---------------- MFMA attention: block = (b, h, pair of 64-q-row tiles)
template<int PREBIAS>
__global__ __launch_bounds__(256) void attn2_kernel(
    const u16* __restrict__ qkv,         // [1536][2304] bf16 q|k|v (q pre-scaled)
    const u16* __restrict__ biasb,       // tt-paired chunk layout (PREBIAS=1)
    const float* __restrict__ atb, const int* __restrict__ sp, const int* __restrict__ spT,
    const float* __restrict__ sp_emb, const float* __restrict__ sp_emb_rev,
    u16* __restrict__ ab)                // [1536][768] bf16
{
  __shared__ __align__(16) u16 Kt[384][32];   // [m][d(24)+pad]
  __shared__ __align__(16) u16 Vt[32][392];   // [d(24)+pad][m] transposed
  __shared__ __align__(16) u16 Qt[128][32];   // both q-tiles
  __shared__ __align__(16) u16 Pw[4][16][32]; // per-wave P chunk
  __shared__ float spc[512], sprc[512];
  const int bid = blockIdx.x;
  const int pair = bid % 3;
  const int h = (bid / 3) % Hh;
  const int b = bid / (3 * Hh);
  const int t = threadIdx.x, lane = t & 63, wave = t >> 6;
  const int ql = lane & 15, hi = lane >> 4;

  for (int idx = t; idx < 384*3; idx += 256) {         // K + V^T staging, 16B loads
    const int m = idx / 3, c = idx - m*3;
    const u16* base = qkv + ((size_t)m*Bb + b)*2304 + h*24 + c*8;
    uint4 kk = *(const uint4*)(base + 768);
    uint4 vv = *(const uint4*)(base + 1536);
    *(uint4*)&Kt[m][c*8] = kk;
    Vt[c*8+0][m] = (u16)(vv.x & 0xffffu); Vt[c*8+1][m] = (u16)(vv.x >> 16);
    Vt[c*8+2][m] = (u16)(vv.y & 0xffffu); Vt[c*8+3][m] = (u16)(vv.y >> 16);
    Vt[c*8+4][m] = (u16)(vv.z & 0xffffu); Vt[c*8+5][m] = (u16)(vv.z >> 16);
    Vt[c*8+6][m] = (u16)(vv.w & 0xffffu); Vt[c*8+7][m] = (u16)(vv.w >> 16);
  }
  for (int idx = t; idx < 384*2; idx += 256)           // K d-pad
    *(uint2*)&Kt[idx>>1][24 + (idx&1)*4] = make_uint2(0u, 0u);
  for (int idx = t; idx < 8*196; idx += 256)           // V^T d-pad rows
    *(unsigned*)((char*)&Vt[24][0] + idx*4) = 0u;
  for (int idx = t; idx < 128*3; idx += 256) {         // Q: both tiles upfront, 16B loads
    const int qr = idx / 3, c = idx - qr*3;
    const u16* base = qkv + ((size_t)(pair*128 + qr)*Bb + b)*2304 + h*24 + c*8;
    *(uint4*)&Qt[qr][c*8] = *(const uint4*)base;
  }
  for (int idx = t; idx < 128*2; idx += 256)           // Q d-pad
    *(uint2*)&Qt[idx>>1][24 + (idx&1)*4] = make_uint2(0u, 0u);
  if (!PREBIAS) {
    for (int i = t; i < 512; i += 256) {
      spc[i]  = sp_emb[(size_t)i*Hh + h];
      sprc[i] = sp_emb_rev[(size_t)i*Hh + h];
    }
  }
  __syncthreads();   // all staging done; loop below is barrier-free

  for (int qi = 0; qi < 2; ++qi) {
    const int ntile = pair*2 + qi;
    const int q0 = ntile*64 + wave*16;
    const int q = q0 + ql;
    const bf16x8 qf = *(const bf16x8*)&Qt[qi*64 + wave*16 + ql][hi*8];

    f32x4 f[24];
    const size_t crow = ((size_t)b*Nn + q)*Nn;
    if (PREBIAS) {
      const u16* bp = biasb + (((size_t)(b*Hh + h)*24 + ntile*4 + wave)*24)*256 + lane*8;
      #pragma unroll
      for (int tt2 = 0; tt2 < 12; ++tt2) {
        uint4 bb = *(const uint4*)(bp + tt2*512);
        {
          bf16x8 kf = *(const bf16x8*)&Kt[(2*tt2)*16 + ql][hi*8];
          f32x4 z = (f32x4){0.f,0.f,0.f,0.f};
          f32x4 s = __builtin_amdgcn_mfma_f32_16x16x32_bf16(kf, qf, z, 0, 0, 0);
          s[0] += b2f((u16)(bb.x & 0xffffu)); s[1] += b2f((u16)(bb.x >> 16));
          s[2] += b2f((u16)(bb.y & 0xffffu)); s[3] += b2f((u16)(bb.y >> 16));
          f[2*tt2] = s;
        }
        {
          bf16x8 kf = *(const bf16x8*)&Kt[(2*tt2+1)*16 + ql][hi*8];
          f32x4 z = (f32x4){0.f,0.f,0.f,0.f};
          f32x4 s = __builtin_amdgcn_mfma_f32_16x16x32_bf16(kf, qf, z, 0, 0, 0);
          s[0] += b2f((u16)(bb.z & 0xffffu)); s[1] += b2f((u16)(bb.z >> 16));
          s[2] += b2f((u16)(bb.w & 0xffffu)); s[3] += b2f((u16)(bb.w >> 16));
          f[2*tt2+1] = s;
        }
      }
    } else {
      #pragma unroll
      for (int tt = 0; tt < 24; ++tt) {
        bf16x8 kf = *(const bf16x8*)&Kt[tt*16 + ql][hi*8];
        f32x4 z = (f32x4){0.f,0.f,0.f,0.f};
        f32x4 s = __builtin_amdgcn_mfma_f32_16x16x32_bf16(kf, qf, z, 0, 0, 0);
        const int off = tt*16 + hi*4;
        int4 s4 = *(const int4*)(sp + crow + off);
        int4 t4 = *(const int4*)(spT + crow + off);
        float4 a4 = *(const float4*)(atb + crow + off);
        s[0] += a4.x + spc[s4.x] + sprc[t4.x];
        s[1] += a4.y + spc[s4.y] + sprc[t4.y];
        s[2] += a4.z + spc[s4.z] + sprc[t4.z];
        s[3] += a4.w + spc[s4.w] + sprc[t4.w];
        f[tt] = s;
      }
    }

    float mx = -3.0e38f;
    #pragma unroll
    for (int tt = 0; tt < 24; ++tt)
      mx = fmaxf(mx, fmaxf(fmaxf(f[tt][0], f[tt][1]), fmaxf(f[tt][2], f[tt][3])));
    mx = fmaxf(mx, __shfl_xor(mx, 16, 64));
    mx = fmaxf(mx, __shfl_xor(mx, 32, 64));
    float sum = 0.f;
    #pragma unroll
    for (int tt = 0; tt < 24; ++tt) {
      #pragma unroll
      for (int j = 0; j < 4; ++j) { f[tt][j] = __expf(f[tt][j] - mx); sum += f[tt][j]; }
    }
    sum += __shfl_xor(sum, 16, 64);
    sum += __shfl_xor(sum, 32, 64);
    const float inv = 1.0f / sum;

    f32x4 o0 = (f32x4){0.f,0.f,0.f,0.f}, o1 = (f32x4){0.f,0.f,0.f,0.f};
    char* prow = (char*)&Pw[wave][ql][0];
    const int swz = (ql & 3) << 4;
    #pragma unroll
    for (int c = 0; c < 12; ++c) {
      unsigned w0 = pkcvt(f[2*c][0],   f[2*c][1]);
      unsigned w1 = pkcvt(f[2*c][2],   f[2*c][3]);
      unsigned w2 = pkcvt(f[2*c+1][0], f[2*c+1][1]);
      unsigned w3 = pkcvt(f[2*c+1][2], f[2*c+1][3]);
      *(unsigned*)(prow + (((hi*8)      ) ^ swz)) = w0;
      *(unsigned*)(prow + (((hi*8) +  4) ^ swz)) = w1;
      *(unsigned*)(prow + (((hi*8) + 32) ^ swz)) = w2;
      *(unsigned*)(prow + (((hi*8) + 36) ^ swz)) = w3;
      bf16x8 a = *(const bf16x8*)(prow + ((hi*16) ^ swz));
      bf16x8 v0 = *(const bf16x8*)&Vt[ql][c*32 + hi*8];
      bf16x8 v1 = *(const bf16x8*)&Vt[16 + ql][c*32 + hi*8];
      o0 = __builtin_amdgcn_mfma_f32_16x16x32_bf16(a, v0, o0, 0, 0, 0);
      o1 = __builtin_amdgcn_mfma_f32_16x16x32_bf16(a, v1, o1, 0, 0, 0);
    }

    #pragma unroll
    for (int j = 0; j < 4; ++j) {
      float invj = __shfl(inv, hi*4 + j, 64);
      const int qg = q0 + hi*4 + j;
      u16* orow = ab + ((size_t)qg*Bb + b)*Ee + h*24;
      orow[ql] = f2b(o0[j] * invj);
      if (ql < 8) orow[16 + ql] = f2b(o1[j] * invj);
    }
  }
}

// ---------------- residual + LayerNorm: wave-per-row, no block barriers, float4 loads
template<int NP>
__global__ __launch_bounds__(256) void ln_kernel(
    const float* __restrict__ xin, const float* __restrict__ delta,
    const float* __restrict__ gamma, const float* __restrict__ beta,
    float* __restrict__ xout, u16* __restrict__ xb)
{
  const int wave = threadIdx.x >> 6, lane = threadIdx.x & 63;
  const int r = blockIdx.x * 4 + wave;
  const size_t base = (size_t)r * Ee;
  const int c0 = lane * 12;
  float v[12];
  #pragma unroll
  for (int i = 0; i < 3; ++i) {
    float4 xv = *(const float4*)(xin + base + c0 + i*4);
    v[i*4+0] = xv.x; v[i*4+1] = xv.y; v[i*4+2] = xv.z; v[i*4+3] = xv.w;
  }
  #pragma unroll
  for (int p = 0; p < NP; ++p) {
    const float* dp = delta + (size_t)p*(Mm*768) + base + c0;
    #pragma unroll
    for (int i = 0; i < 3; ++i) {
      float4 dv = *(const float4*)(dp + i*4);
      v[i*4+0] += dv.x; v[i*4+1] += dv.y; v[i*4+2] += dv.z; v[i*4+3] += dv.w;
    }
  }
  float s = 0.f;
  #pragma unroll
  for (int i = 0; i < 12; ++i) s += v[i];
  #pragma unroll
  for (int off = 1; off < 64; off <<= 1) s += __shfl_xor(s, off, 64);
  const float mean = s * (1.0f / 768.0f);
  float qs = 0.f;
  #pragma unroll
  for (int i = 0; i < 12; ++i) { float d = v[i] - mean; qs += d * d; }
  #pragma unroll
  for (int off = 1; off < 64; off <<= 1) qs += __shfl_xor(qs, off, 64);
  const float rstd = rsqrtf(qs * (1.0f / 768.0f) + 1e-5f);
  float o[12];
  #pragma unroll
  for (int i = 0; i < 3; ++i) {
    float4 g4 = *(const float4*)(gamma + c0 + i*4);
    float4 b4 = *(const float4*)(beta + c0 + i*4);
    o[i*4+0] = (v[i*4+0] - mean) * rstd * g4.x + b4.x;
    o[i*4+1] = (v[i*4+1] - mean) * rstd * g4.y + b4.y;
    o[i*4+2] = (v[i*4+2] - mean) * rstd * g4.z + b4.z;
    o[i*4+3] = (v[i*4+3] - mean) * rstd * g4.w + b4.w;
    *(float4*)(xout + base + c0 + i*4) = make_float4(o[i*4+0], o[i*4+1], o[i*4+2], o[i*4+3]);
  }
  #pragma unroll
  for (int i = 0; i < 3; ++i) {
    uint2 u;
    u.x = pkcvt(o[i*4+0], o[i*4+1]);
    u.y = pkcvt(o[i*4+2], o[i*4+3]);
    *(uint2*)(xb + base + c0 + i*4) = u;
  }
}

extern "C" void kernel_launch(void* const* d_in, const int* in_sizes, int n_in,
                              void* d_out, int out_size, void* d_ws, size_t ws_size,
                              hipStream_t stream) {
  const int*   node_type  = (const int*)d_in[0];
  const float* nif        = (const float*)d_in[1];
  const int*   in_deg     = (const int*)d_in[2];
  const int*   out_deg    = (const int*)d_in[3];
  const float* atb        = (const float*)d_in[4];
  const int*   sp         = (const int*)d_in[5];
  const float* node_emb   = (const float*)d_in[6];
  const float* ind_emb    = (const float*)d_in[7];
  const float* outd_emb   = (const float*)d_in[8];
  const float* sp_emb     = (const float*)d_in[9];
  const float* sp_emb_rev = (const float*)d_in[10];
  const float* Wq = (const float*)d_in[11]; const float* bq = (const float*)d_in[12];
  const float* Wk = (const float*)d_in[13]; const float* bk = (const float*)d_in[14];
  const float* Wv = (const float*)d_in[15]; const float* bv = (const float*)d_in[16];
  const float* Wo = (const float*)d_in[17]; const float* bo = (const float*)d_in[18];
  const float* W1 = (const float*)d_in[19]; const float* b1 = (const float*)d_in[20];
  const float* W2 = (const float*)d_in[21]; const float* b2 = (const float*)d_in[22];
  const float* ln1s = (const float*)d_in[23]; const float* ln1b = (const float*)d_in[24];
  const float* ln2s = (const float*)d_in[25]; const float* ln2b = (const float*)d_in[26];

  char* ws = (char*)d_ws;
  float* x      = (float*)(ws);                    //  4,718,592
  u16*   xb     = (u16*)(ws +  4718592);           //  2,359,296
  u16*   qkvb16 = (u16*)(ws +  7077888);           //  7,077,888
  u16*   abuf   = (u16*)(ws + 14155776);           //  2,359,296
  u16*   hb     = (u16*)(ws + 16515072);           //  9,437,184
  float* obufP  = (float*)(ws + 25952256);         // 18,874,368 (4 partials)
  int*   spTb   = (int*)(ws + 44826624);           //  2,359,296
  u16*   biasb  = (u16*)(ws + 47185920);           // 37,748,736 -> 84,934,656
  u16*   wTs0   = (u16*)(ws + 84934656);           // 14,155,776
  u16*   wTs1   = (u16*)(ws + 99090432);           // 14,155,776 -> 113,246,208
  const bool useBias = ws_size >= 113246208ull;
  u16* slots[2] = { wTs0, wTs1 };

  // fused upfront: embed | spT | wconv(l0)  (all independent)
  prep_kernel<<<3840, 256, 0, stream>>>(node_type, nif, in_deg, out_deg,
                                        node_emb, ind_emb, outd_emb, x, xb,
                                        sp, spTb,
                                        Wq, Wk, Wv, Wo, W1, W2, slots[0]);

  const float scaleQ = 0.2041241452319315f;  // 24^-0.5

  for (int l = 0; l < Ll; ++l) {
    const float *bql = bq + (size_t)l*Ee, *bkl = bk + (size_t)l*Ee, *bvl = bv + (size_t)l*Ee;
    const float *bol = bo + (size_t)l*Ee;
    const float *b1l = b1 + (size_t)l*Ff, *b2l = b2 + (size_t)l*Ee;

    u16* slot = slots[l & 1];
    u16* slotN = slots[(l + 1) & 1];
    const u16* qkvT = slot;
    const u16* woT  = slot + 1769472;
    const u16* w1T  = slot + 2359296;
    const u16* w2T  = slot + 4718592;

    // QKV: [1536,768] @ [2304,768]^T -> bf16 [1536][2304]
    // layer 0 (useBias): fused with bias_pre (both depend only on prep outputs)
    if (l == 0 && useBias)
      qkv0b_kernel<<<3504, 256, 0, stream>>>(xb, qkvT, bql, bkl, bvl, scaleQ, qkvb16,
                                             atb, sp, spTb, sp_emb, sp_emb_rev, biasb);
    else
      gemm3_kernel<0><<<dim3(12, 36), 256, 0, stream>>>(xb, qkvT, bql, bkl, bvl,
                                                        768, 768, scaleQ, nullptr, qkvb16);
    if (useBias)
      attn2_kernel<1><<<384, 256, 0, stream>>>(qkvb16, biasb, atb, sp, spTb,
                                               sp_emb, sp_emb_rev, abuf);
    else
      attn2_kernel<0><<<384, 256, 0, stream>>>(qkvb16, nullptr, atb, sp, spTb,
                                               sp_emb, sp_emb_rev, abuf);
    // O-proj: split-K 2 -> partials
    gemm3_kernel<1><<<dim3(12, 12, 2), 256, 0, stream>>>(abuf, woT, bol, bol, bol,
                                                         768, 384, 1.0f, obufP, nullptr);
    ln_kernel<2><<<Mm/4, 256, 0, stream>>>(x, obufP, ln1s + (size_t)l*Ee, ln1b + (size_t)l*Ee, x, xb);
    // FFN1 + gelu -> bf16 hidden
    gemm3_kernel<2><<<dim3(12, 48), 256, 0, stream>>>(xb, w1T, b1l, b1l, b1l,
                                                      768, 768, 1.0f, nullptr, hb);
    // FFN2 split-K 4 (blocks 0..575)  FUSED with  wconv(layer l+1) -> other slot
    ffn2w_kernel<<<2304, 256, 0, stream>>>(hb, w2T, b2l, obufP,
                                           Wq, Wk, Wv, Wo, W1, W2,
                                           l + 1, slotN, (l + 1 < Ll) ? 1 : 0);
    float* xdst = (l == Ll - 1) ? (float*)d_out : x;
    ln_kernel<4><<<Mm/4, 256, 0, stream>>>(x, obufP, ln2s + (size_t)l*Ee, ln2b + (size_t)l*Ee, xdst, xb);
  }
}